// Round 8
// baseline (671.060 us; speedup 1.0000x reference)
//
#include <hip/hip_runtime.h>
#include <hip/hip_bf16.h>

typedef __attribute__((ext_vector_type(8))) short s16x8;
typedef __attribute__((ext_vector_type(4))) float f32x4;
typedef unsigned short u16;
typedef unsigned int u32;

__device__ __forceinline__ u16 f2b(float f) {
    u32 u = __float_as_uint(f);
    u32 r = (u + 0x7fffu + ((u >> 16) & 1u)) >> 16;  // RNE bf16
    return (u16)r;
}
__device__ __forceinline__ float b2f(u16 b) {
    return __uint_as_float(((u32)b) << 16);
}

#define MFMA16(a, b, c) __builtin_amdgcn_mfma_f32_16x16x32_bf16(a, b, c, 0, 0, 0)
#define GLDS(gp, lp)                                                              \
    __builtin_amdgcn_global_load_lds((const __attribute__((address_space(1))) void*)(gp), \
                                     (__attribute__((address_space(3))) void*)(lp), 16, 0, 0)

// ---------------- elementwise: f32 -> bf16 ----------------
__global__ void k_f2b(const float* __restrict__ in, u16* __restrict__ out, int n4) {
    int i = blockIdx.x * 256 + threadIdx.x;
    if (i >= n4) return;
    float4 v = ((const float4*)in)[i];
    ushort4 o;
    o.x = f2b(v.x); o.y = f2b(v.y); o.z = f2b(v.z); o.w = f2b(v.w);
    ((ushort4*)out)[i] = o;
}

// ---------------- weight transpose+convert: W[K,N] f32 -> Wt[N,K] bf16 ----------------
__global__ void k_wtrans(const float* __restrict__ W, u16* __restrict__ Wt, int K, int N) {
    __shared__ float t[32][33];
    int bx = blockIdx.x * 32, by = blockIdx.y * 32;
    int tx = threadIdx.x, ty = threadIdx.y;
    for (int i = 0; i < 32; i += 8)
        t[ty + i][tx] = W[(size_t)(by + ty + i) * N + bx + tx];
    __syncthreads();
    for (int i = 0; i < 32; i += 8)
        Wt[(size_t)(bx + ty + i) * K + by + tx] = f2b(t[tx][ty + i]);
}

// ---------------- fused QKV GEMM: [4096,1024]@[3072,1024]^T, epilogue writes Qa/Qc/Ka/Kc/Vt bf16 ----------------
__global__ __launch_bounds__(256) void gemm_qkv(const u16* __restrict__ A, const u16* __restrict__ Bt,
                                                const float* __restrict__ bq, const float* __restrict__ bk,
                                                const float* __restrict__ bv, const float* __restrict__ rel,
                                                u16* __restrict__ Qa, u16* __restrict__ Qc,
                                                u16* __restrict__ Ka, u16* __restrict__ Kc,
                                                u16* __restrict__ Vt) {
    __shared__ __align__(16) short lA[128 * 64];
    __shared__ __align__(16) short lB[128 * 64];
    const int tid = threadIdx.x, lane = tid & 63, w = tid >> 6;
    const int l15 = lane & 15, lg = lane >> 4;
    const int wr = w >> 1, wc = w & 1;
    const int m0 = blockIdx.y * 128, n0 = blockIdx.x * 128;
    const int KK = 1024;
    f32x4 acc[4][4] = {};

    for (int k0 = 0; k0 < KK; k0 += 64) {
        #pragma unroll
        for (int i = 0; i < 4; i++) {
            int chunk = w * 4 + i;
            int arow = m0 + chunk * 8 + (lane >> 3);
            GLDS(A + (size_t)arow * KK + k0 + (lane & 7) * 8, (short*)lA + chunk * 512);
            int brow = n0 + chunk * 8 + (lane >> 3);
            GLDS(Bt + (size_t)brow * KK + k0 + (lane & 7) * 8, (short*)lB + chunk * 512);
        }
        __syncthreads();
        #pragma unroll
        for (int ks = 0; ks < 2; ks++) {
            s16x8 af[4], bfr[4];
            #pragma unroll
            for (int m = 0; m < 4; m++)
                af[m] = *(const s16x8*)&lA[(wr * 64 + m * 16 + l15) * 64 + ks * 32 + lg * 8];
            #pragma unroll
            for (int n = 0; n < 4; n++)
                bfr[n] = *(const s16x8*)&lB[(wc * 64 + n * 16 + l15) * 64 + ks * 32 + lg * 8];
            #pragma unroll
            for (int m = 0; m < 4; m++)
                #pragma unroll
                for (int n = 0; n < 4; n++)
                    acc[m][n] = MFMA16(af[m], bfr[n], acc[m][n]);
        }
        __syncthreads();
    }
    const int rbase = m0 + wr * 64, cbase = n0 + wc * 64;
    const int seg = cbase >> 10;  // uniform per block (128-wide tiles)
    #pragma unroll
    for (int m = 0; m < 4; m++)
        #pragma unroll
        for (int n = 0; n < 4; n++) {
            int col = cbase + n * 16 + l15;
            int c1 = col & 1023, d = col & 63;
            int row0 = rbase + m * 16 + lg * 4;
            if (seg == 0) {
                float bb = bq[c1], r0 = rel[d], r1 = rel[64 + d];
                #pragma unroll
                for (int r = 0; r < 4; r++) {
                    float v = acc[m][n][r] + bb;
                    size_t o = (size_t)(row0 + r) * 1024 + c1;
                    Qa[o] = f2b(v + r0);
                    Qc[o] = f2b(v + r1);
                }
            } else if (seg == 1) {
                float bb = bk[c1], r0 = rel[d], r1 = rel[64 + d];
                #pragma unroll
                for (int r = 0; r < 4; r++) {
                    float v = acc[m][n][r] + bb;
                    size_t o = (size_t)(row0 + r) * 1024 + c1;
                    Ka[o] = f2b(v + r0);
                    Kc[o] = f2b(v + r1);
                }
            } else {
                float bb = bv[c1];
                #pragma unroll
                for (int r = 0; r < 4; r++) {
                    int row = row0 + r;
                    size_t o = (size_t)(row >> 6) * 65536 + (size_t)d * 1024 + (row & 63) * 16 + (c1 >> 6);
                    Vt[o] = f2b(acc[m][n][r] + bb);
                }
            }
        }
}

// ---------------- GEMM 128x128, EPI 1: bf16(relu(acc+bias)) ----------------
template <int EPI>
__global__ __launch_bounds__(256) void gemm_bt(const u16* __restrict__ A, const u16* __restrict__ Bt,
                                               void* __restrict__ Cv, int M, int N, int K,
                                               const float* __restrict__ bias) {
    __shared__ __align__(16) short lA[128 * 64];
    __shared__ __align__(16) short lB[128 * 64];
    const int tid = threadIdx.x, lane = tid & 63, w = tid >> 6;
    const int l15 = lane & 15, lg = lane >> 4;
    const int wr = w >> 1, wc = w & 1;
    const int m0 = blockIdx.y * 128, n0 = blockIdx.x * 128;
    f32x4 acc[4][4] = {};

    for (int k0 = 0; k0 < K; k0 += 64) {
        #pragma unroll
        for (int i = 0; i < 4; i++) {
            int chunk = w * 4 + i;
            int arow = m0 + chunk * 8 + (lane >> 3);
            GLDS(A + (size_t)arow * K + k0 + (lane & 7) * 8, (short*)lA + chunk * 512);
            int brow = n0 + chunk * 8 + (lane >> 3);
            GLDS(Bt + (size_t)brow * K + k0 + (lane & 7) * 8, (short*)lB + chunk * 512);
        }
        __syncthreads();
        #pragma unroll
        for (int ks = 0; ks < 2; ks++) {
            s16x8 af[4], bfr[4];
            #pragma unroll
            for (int m = 0; m < 4; m++)
                af[m] = *(const s16x8*)&lA[(wr * 64 + m * 16 + l15) * 64 + ks * 32 + lg * 8];
            #pragma unroll
            for (int n = 0; n < 4; n++)
                bfr[n] = *(const s16x8*)&lB[(wc * 64 + n * 16 + l15) * 64 + ks * 32 + lg * 8];
            #pragma unroll
            for (int m = 0; m < 4; m++)
                #pragma unroll
                for (int n = 0; n < 4; n++)
                    acc[m][n] = MFMA16(af[m], bfr[n], acc[m][n]);
        }
        __syncthreads();
    }
    const int rbase = m0 + wr * 64, cbase = n0 + wc * 64;
    #pragma unroll
    for (int m = 0; m < 4; m++)
        #pragma unroll
        for (int n = 0; n < 4; n++) {
            int col = cbase + n * 16 + l15;
            int row0 = rbase + m * 16 + lg * 4;
            u16* C = (u16*)Cv;
            float bv = bias[col];
            #pragma unroll
            for (int r = 0; r < 4; r++)
                C[(size_t)(row0 + r) * N + col] = f2b(fmaxf(acc[m][n][r] + bv, 0.f));
        }
}

// ---------------- GEMM 128x64 f32-out ----------------
__global__ __launch_bounds__(256) void gemm_bt64(const u16* __restrict__ A, const u16* __restrict__ Bt,
                                                 float* __restrict__ C, int M, int N, int K) {
    __shared__ __align__(16) short lA[128 * 64];
    __shared__ __align__(16) short lB[64 * 64];
    const int tid = threadIdx.x, lane = tid & 63, w = tid >> 6;
    const int l15 = lane & 15, lg = lane >> 4;
    const int m0 = blockIdx.y * 128, n0 = blockIdx.x * 64;
    f32x4 acc[2][4] = {};

    for (int k0 = 0; k0 < K; k0 += 64) {
        #pragma unroll
        for (int i = 0; i < 4; i++) {
            int chunk = w * 4 + i;
            int arow = m0 + chunk * 8 + (lane >> 3);
            GLDS(A + (size_t)arow * K + k0 + (lane & 7) * 8, (short*)lA + chunk * 512);
        }
        #pragma unroll
        for (int i = 0; i < 2; i++) {
            int chunk = w * 2 + i;
            int brow = n0 + chunk * 8 + (lane >> 3);
            GLDS(Bt + (size_t)brow * K + k0 + (lane & 7) * 8, (short*)lB + chunk * 512);
        }
        __syncthreads();
        #pragma unroll
        for (int ks = 0; ks < 2; ks++) {
            s16x8 af[2], bfr[4];
            #pragma unroll
            for (int m = 0; m < 2; m++)
                af[m] = *(const s16x8*)&lA[(w * 32 + m * 16 + l15) * 64 + ks * 32 + lg * 8];
            #pragma unroll
            for (int n = 0; n < 4; n++)
                bfr[n] = *(const s16x8*)&lB[(n * 16 + l15) * 64 + ks * 32 + lg * 8];
            #pragma unroll
            for (int m = 0; m < 2; m++)
                #pragma unroll
                for (int n = 0; n < 4; n++)
                    acc[m][n] = MFMA16(af[m], bfr[n], acc[m][n]);
        }
        __syncthreads();
    }
    #pragma unroll
    for (int m = 0; m < 2; m++)
        #pragma unroll
        for (int n = 0; n < 4; n++) {
            int col = n0 + n * 16 + l15;
            int row0 = m0 + w * 32 + m * 16 + lg * 4;
            #pragma unroll
            for (int r = 0; r < 4; r++)
                C[(size_t)(row0 + r) * N + col] = acc[m][n][r];
        }
}

// ---------------- stage A (both maps): S=QK^T, E=exp(S/8) -> linear bf16 blobs + denominators ----------------
// grid 1024 (XCD-swizzled -> (qt,g)), 4 waves; wave w owns q rows qt*64+w*16..+15, full k sweep.
// E blob layout = stage-B load order: [g][qt][w][it][ks][lane] x 16B.
__global__ __launch_bounds__(256) void k_qke2(const u16* __restrict__ Qa, const u16* __restrict__ Qc,
                                              const u16* __restrict__ Ka, const u16* __restrict__ Kc,
                                              u16* __restrict__ Ea, u16* __restrict__ Ec,
                                              float* __restrict__ denA, float* __restrict__ denC) {
    const int bid = blockIdx.x;
    const int xcd = bid & 7, j = bid >> 3;
    const int g = xcd * 8 + (j & 7), qt = j >> 3;
    const int tid = threadIdx.x, lane = tid & 63, w = tid >> 6;
    const int l15 = lane & 15, lg = lane >> 4;
    __shared__ __align__(16) float lE[2][4][16][68];

    const int q0 = qt * 64 + w * 16;
    const size_t gQ = (size_t)g * 65536;
    const size_t ebase = ((((size_t)g * 16 + qt) * 4 + w) * 16384) + (size_t)lane * 8;
    const float scale = 0.125f;

    s16x8 qa[2], qc[2];
    #pragma unroll
    for (int ks = 0; ks < 2; ks++) {
        size_t off = gQ + (size_t)(q0 + l15) * 64 + ks * 32 + lg * 8;
        qa[ks] = *(const s16x8*)(Qa + off);
        qc[ks] = *(const s16x8*)(Qc + off);
    }

    float la[4] = {0.f, 0.f, 0.f, 0.f}, lc[4] = {0.f, 0.f, 0.f, 0.f};

    #pragma unroll 1
    for (int it = 0; it < 16; it++) {
        const int kb = it * 64;
        f32x4 sa[4] = {}, sc[4] = {};
        #pragma unroll
        for (int ks = 0; ks < 2; ks++)
            #pragma unroll
            for (int n = 0; n < 4; n++) {
                size_t koff = gQ + (size_t)(kb + n * 16 + l15) * 64 + ks * 32 + lg * 8;
                s16x8 kfa = *(const s16x8*)(Ka + koff);
                s16x8 kfc = *(const s16x8*)(Kc + koff);
                sa[n] = MFMA16(qa[ks], kfa, sa[n]);
                sc[n] = MFMA16(qc[ks], kfc, sc[n]);
            }
        #pragma unroll
        for (int n = 0; n < 4; n++)
            #pragma unroll
            for (int r = 0; r < 4; r++) {
                float ea = __expf(sa[n][r] * scale);
                float ec = __expf(sc[n][r] * scale);
                la[r] += ea;
                lc[r] += ec;
                lE[0][w][lg * 4 + r][n * 16 + l15] = ea;
                lE[1][w][lg * 4 + r][n * 16 + l15] = ec;
            }
        #pragma unroll
        for (int ks = 0; ks < 2; ks++) {
            const float* ep = &lE[0][w][l15][ks * 32 + lg * 8];
            float4 e0 = *(const float4*)ep, e1 = *(const float4*)(ep + 4);
            uint4 st;
            st.x = (u32)f2b(e0.x) | ((u32)f2b(e0.y) << 16);
            st.y = (u32)f2b(e0.z) | ((u32)f2b(e0.w) << 16);
            st.z = (u32)f2b(e1.x) | ((u32)f2b(e1.y) << 16);
            st.w = (u32)f2b(e1.z) | ((u32)f2b(e1.w) << 16);
            *(uint4*)(Ea + ebase + (size_t)it * 1024 + ks * 512) = st;
            const float* fp = &lE[1][w][l15][ks * 32 + lg * 8];
            float4 f0 = *(const float4*)fp, f1 = *(const float4*)(fp + 4);
            uint4 st2;
            st2.x = (u32)f2b(f0.x) | ((u32)f2b(f0.y) << 16);
            st2.y = (u32)f2b(f0.z) | ((u32)f2b(f0.w) << 16);
            st2.z = (u32)f2b(f1.x) | ((u32)f2b(f1.y) << 16);
            st2.w = (u32)f2b(f1.z) | ((u32)f2b(f1.w) << 16);
            *(uint4*)(Ec + ebase + (size_t)it * 1024 + ks * 512) = st2;
        }
    }
    #pragma unroll
    for (int r = 0; r < 4; r++)
        #pragma unroll
        for (int m = 8; m >= 1; m >>= 1) {
            la[r] += __shfl_xor(la[r], m);
            lc[r] += __shfl_xor(lc[r], m);
        }
    if (l15 == 0) {
        #pragma unroll
        for (int r = 0; r < 4; r++) {
            denA[g * 1024 + q0 + lg * 4 + r] = la[r];
            denC[g * 1024 + q0 + lg * 4 + r] = lc[r];
        }
    }
}

// ---------------- stage B (both maps): ctx = (Ea o Ma)@V/denA + (Ec o Mc)@V/denC ----------------
// Pure stream: per iter 20 mutually independent loads, no LDS, no exp, no QK.
__global__ __launch_bounds__(256) void k_pv2(const u16* __restrict__ Ea, const u16* __restrict__ Ec,
                                             const u16* __restrict__ Vt,
                                             const float* __restrict__ adjm, const float* __restrict__ comm,
                                             const float* __restrict__ denA, const float* __restrict__ denC,
                                             u16* __restrict__ ctx) {
    const int bid = blockIdx.x;
    const int xcd = bid & 7, j = bid >> 3;
    const int g = xcd * 8 + (j & 7), qt = j >> 3;
    const int tid = threadIdx.x, lane = tid & 63, w = tid >> 6;
    const int l15 = lane & 15, lg = lane >> 4;

    const int q0 = qt * 64 + w * 16;
    const size_t gQ = (size_t)g * 65536;
    const size_t mroff = (size_t)g * 1048576 + (size_t)(q0 + l15) * 1024 + lg * 8;
    const float* __restrict__ mrow_a = adjm + mroff;
    const float* __restrict__ mrow_c = comm + mroff;
    const size_t ebase = ((((size_t)g * 16 + qt) * 4 + w) * 16384) + (size_t)lane * 8;

    f32x4 ca[4] = {}, cc[4] = {};

    #pragma unroll 2
    for (int it = 0; it < 16; it++) {
        const int kb = it * 64;
        s16x8 ea[2], ec[2], vf[8];
        float4 ma[4], mc[4];
        #pragma unroll
        for (int ks = 0; ks < 2; ks++) {
            ea[ks] = *(const s16x8*)(Ea + ebase + (size_t)it * 1024 + ks * 512);
            ec[ks] = *(const s16x8*)(Ec + ebase + (size_t)it * 1024 + ks * 512);
            ma[ks * 2 + 0] = *(const float4*)(mrow_a + kb + ks * 32);
            ma[ks * 2 + 1] = *(const float4*)(mrow_a + kb + ks * 32 + 4);
            mc[ks * 2 + 0] = *(const float4*)(mrow_c + kb + ks * 32);
            mc[ks * 2 + 1] = *(const float4*)(mrow_c + kb + ks * 32 + 4);
            #pragma unroll
            for (int d = 0; d < 4; d++)
                vf[ks * 4 + d] = *(const s16x8*)(Vt + gQ + (size_t)(d * 16 + l15) * 1024 + kb + ks * 32 + lg * 8);
        }
        #pragma unroll
        for (int ks = 0; ks < 2; ks++) {
            union { s16x8 v; u16 u[8]; } pa, pc;
            pa.u[0] = f2b(b2f((u16)ea[ks][0]) * ma[ks * 2].x);
            pa.u[1] = f2b(b2f((u16)ea[ks][1]) * ma[ks * 2].y);
            pa.u[2] = f2b(b2f((u16)ea[ks][2]) * ma[ks * 2].z);
            pa.u[3] = f2b(b2f((u16)ea[ks][3]) * ma[ks * 2].w);
            pa.u[4] = f2b(b2f((u16)ea[ks][4]) * ma[ks * 2 + 1].x);
            pa.u[5] = f2b(b2f((u16)ea[ks][5]) * ma[ks * 2 + 1].y);
            pa.u[6] = f2b(b2f((u16)ea[ks][6]) * ma[ks * 2 + 1].z);
            pa.u[7] = f2b(b2f((u16)ea[ks][7]) * ma[ks * 2 + 1].w);
            pc.u[0] = f2b(b2f((u16)ec[ks][0]) * mc[ks * 2].x);
            pc.u[1] = f2b(b2f((u16)ec[ks][1]) * mc[ks * 2].y);
            pc.u[2] = f2b(b2f((u16)ec[ks][2]) * mc[ks * 2].z);
            pc.u[3] = f2b(b2f((u16)ec[ks][3]) * mc[ks * 2].w);
            pc.u[4] = f2b(b2f((u16)ec[ks][4]) * mc[ks * 2 + 1].x);
            pc.u[5] = f2b(b2f((u16)ec[ks][5]) * mc[ks * 2 + 1].y);
            pc.u[6] = f2b(b2f((u16)ec[ks][6]) * mc[ks * 2 + 1].z);
            pc.u[7] = f2b(b2f((u16)ec[ks][7]) * mc[ks * 2 + 1].w);
            #pragma unroll
            for (int d = 0; d < 4; d++) {
                ca[d] = MFMA16(pa.v, vf[ks * 4 + d], ca[d]);
                cc[d] = MFMA16(pc.v, vf[ks * 4 + d], cc[d]);
            }
        }
    }
    float ila[4], ilc[4];
    #pragma unroll
    for (int r = 0; r < 4; r++) {
        ila[r] = 1.f / denA[g * 1024 + q0 + lg * 4 + r];
        ilc[r] = 1.f / denC[g * 1024 + q0 + lg * 4 + r];
    }
    #pragma unroll
    for (int r = 0; r < 4; r++) {
        int row = q0 + lg * 4 + r;
        #pragma unroll
        for (int d = 0; d < 4; d++)
            ctx[gQ + (size_t)row * 64 + d * 16 + l15] = f2b(ca[d][r] * ila[r] + cc[d][r] * ilc[r]);
    }
}

// ---------------- row LayerNorm ----------------
__global__ __launch_bounds__(256) void k_ln(const float* __restrict__ a, const float* __restrict__ bias,
                                            const float* __restrict__ resid, const float* __restrict__ gamma,
                                            const float* __restrict__ beta, float* __restrict__ out,
                                            u16* __restrict__ outb) {
    const int row = blockIdx.x, tid = threadIdx.x;
    const size_t base = (size_t)row * 1024 + tid * 4;
    float4 av = *(const float4*)(a + base);
    float4 rv = *(const float4*)(resid + base);
    float4 bv = *(const float4*)(bias + tid * 4);
    float t0 = av.x + rv.x + bv.x, t1 = av.y + rv.y + bv.y;
    float t2 = av.z + rv.z + bv.z, t3 = av.w + rv.w + bv.w;
    __shared__ float red[4];
    float s = t0 + t1 + t2 + t3;
    #pragma unroll
    for (int m = 32; m >= 1; m >>= 1) s += __shfl_xor(s, m);
    int w = tid >> 6;
    if ((tid & 63) == 0) red[w] = s;
    __syncthreads();
    float mean = (red[0] + red[1] + red[2] + red[3]) * (1.f / 1024.f);
    float d0 = t0 - mean, d1 = t1 - mean, d2 = t2 - mean, d3 = t3 - mean;
    float q = d0 * d0 + d1 * d1 + d2 * d2 + d3 * d3;
    __syncthreads();
    #pragma unroll
    for (int m = 32; m >= 1; m >>= 1) q += __shfl_xor(q, m);
    if ((tid & 63) == 0) red[w] = q;
    __syncthreads();
    float var = (red[0] + red[1] + red[2] + red[3]) * (1.f / 1024.f);
    float rs = rsqrtf(var + 1e-5f);
    float4 gv = *(const float4*)(gamma + tid * 4);
    float4 bev = *(const float4*)(beta + tid * 4);
    float o0 = d0 * rs * gv.x + bev.x, o1 = d1 * rs * gv.y + bev.y;
    float o2 = d2 * rs * gv.z + bev.z, o3 = d3 * rs * gv.w + bev.w;
    *(float4*)(out + base) = make_float4(o0, o1, o2, o3);
    if (outb) {
        ushort4 ob;
        ob.x = f2b(o0); ob.y = f2b(o1); ob.z = f2b(o2); ob.w = f2b(o3);
        *(ushort4*)(outb + base) = ob;
    }
}

extern "C" void kernel_launch(void* const* d_in, const int* in_sizes, int n_in,
                              void* d_out, int out_size, void* d_ws, size_t ws_size,
                              hipStream_t stream) {
    const float* x    = (const float*)d_in[0];
    const float* adjm = (const float*)d_in[1];
    const float* comm = (const float*)d_in[2];
    const float* rel  = (const float*)d_in[3];
    const float* Wq   = (const float*)d_in[4];
    const float* bq   = (const float*)d_in[5];
    const float* Wk   = (const float*)d_in[6];
    const float* bk   = (const float*)d_in[7];
    const float* Wv   = (const float*)d_in[8];
    const float* bv   = (const float*)d_in[9];
    const float* Wo   = (const float*)d_in[10];
    const float* bo   = (const float*)d_in[11];
    const float* g1   = (const float*)d_in[12];
    const float* be1  = (const float*)d_in[13];
    const float* W1   = (const float*)d_in[14];
    const float* b1   = (const float*)d_in[15];
    const float* W2   = (const float*)d_in[16];
    const float* b2   = (const float*)d_in[17];
    const float* g2   = (const float*)d_in[18];
    const float* be2  = (const float*)d_in[19];
    float* out = (float*)d_out;

    char* ws = (char*)d_ws;
    const size_t MB = 1048576;
    u16*   xb    = (u16*)(ws + 0 * MB);      // 8 MiB (dead after gemm_qkv)
    u16*   Wqkvt = (u16*)(ws + 8 * MB);      // 6 MiB
    u16*   Wot   = (u16*)(ws + 14 * MB);     // 2 MiB
    u16*   W1t   = (u16*)(ws + 16 * MB);     // 8 MiB
    u16*   W2t   = (u16*)(ws + 24 * MB);     // 8 MiB (live through FFN2)
    u16*   Qab   = (u16*)(ws + 32 * MB);     // 8 MiB each [32,72)
    u16*   Qcb   = (u16*)(ws + 40 * MB);
    u16*   Kab   = (u16*)(ws + 48 * MB);
    u16*   Kcb   = (u16*)(ws + 56 * MB);
    u16*   Vtb   = (u16*)(ws + 64 * MB);
    u16*   Eab   = (u16*)(ws + 72 * MB);     // 128 MiB [72,200)
    u16*   Ecb   = (u16*)(ws + 200 * MB);    // 128 MiB [200,328)
    float* denA  = (float*)(ws + 328 * MB);  // 256 KiB
    float* denC  = (float*)(ws + 329 * MB);  // 256 KiB
    u16*   ctx   = (u16*)(ws + 330 * MB);    // 8 MiB (dead after Wo gemm)
    float* ctxWo = (float*)(ws + 32 * MB);   // reuse Qab/Qcb (dead after attn)
    float* out1  = (float*)(ws + 48 * MB);   // reuse Kab/Kcb (live to LN2)
    u16*   out1b = (u16*)(ws + 64 * MB);     // reuse Vtb
    u16*   rb    = (u16*)(ws + 72 * MB);     // 32 MiB reuse Eab (dead after k_pv2)
    float* ff2   = (float*)(ws + 0 * MB);    // 16 MiB reuse xb+weights (dead)

    dim3 tb(32, 8);
    // 1. casts / weight prep
    k_f2b<<<4096, 256, 0, stream>>>(x, xb, 1048576);
    k_wtrans<<<dim3(32, 32), tb, 0, stream>>>(Wq, Wqkvt, 1024, 1024);
    k_wtrans<<<dim3(32, 32), tb, 0, stream>>>(Wk, Wqkvt + 1024 * 1024, 1024, 1024);
    k_wtrans<<<dim3(32, 32), tb, 0, stream>>>(Wv, Wqkvt + 2 * 1024 * 1024, 1024, 1024);
    k_wtrans<<<dim3(32, 32), tb, 0, stream>>>(Wo, Wot, 1024, 1024);
    k_wtrans<<<dim3(128, 32), tb, 0, stream>>>(W1, W1t, 1024, 4096);
    k_wtrans<<<dim3(32, 128), tb, 0, stream>>>(W2, W2t, 4096, 1024);
    // 2. fused QKV projection + epilogues (Qa/Qc/Ka/Kc flat, Vt transposed)
    gemm_qkv<<<dim3(24, 32), 256, 0, stream>>>(xb, Wqkvt, bq, bk, bv, rel,
                                               Qab, Qcb, Kab, Kcb, Vtb);
    // 3. attention: merged two-stage (proven streaming structure)
    k_qke2<<<1024, 256, 0, stream>>>(Qab, Qcb, Kab, Kcb, Eab, Ecb, denA, denC);
    k_pv2<<<1024, 256, 0, stream>>>(Eab, Ecb, Vtb, adjm, comm, denA, denC, ctx);
    // 4. output projection + LN1
    gemm_bt64<<<dim3(16, 32), 256, 0, stream>>>(ctx, Wot, ctxWo, 4096, 1024, 1024);
    k_ln<<<4096, 256, 0, stream>>>(ctxWo, bo, x, g1, be1, out1, out1b);
    // 5. FFN
    gemm_bt<1><<<dim3(32, 32), 256, 0, stream>>>(out1b, W1t, rb, 4096, 4096, 1024, b1);
    gemm_bt64<<<dim3(16, 32), 256, 0, stream>>>(rb, W2t, ff2, 4096, 1024, 4096);
    // 6. LN2 -> final output
    k_ln<<<4096, 256, 0, stream>>>(ff2, b2, out1, g2, be2, out, nullptr);
}

// Round 9
// 654.107 us; speedup vs baseline: 1.0259x; 1.0259x over previous
//
#include <hip/hip_runtime.h>
#include <hip/hip_bf16.h>

typedef __attribute__((ext_vector_type(8))) short s16x8;
typedef __attribute__((ext_vector_type(4))) float f32x4;
typedef unsigned short u16;
typedef unsigned int u32;

__device__ __forceinline__ u16 f2b(float f) {
    u32 u = __float_as_uint(f);
    u32 r = (u + 0x7fffu + ((u >> 16) & 1u)) >> 16;  // RNE bf16
    return (u16)r;
}
__device__ __forceinline__ float b2f(u16 b) {
    return __uint_as_float(((u32)b) << 16);
}

#define MFMA16(a, b, c) __builtin_amdgcn_mfma_f32_16x16x32_bf16(a, b, c, 0, 0, 0)
#define GLDS(gp, lp)                                                              \
    __builtin_amdgcn_global_load_lds((const __attribute__((address_space(1))) void*)(gp), \
                                     (__attribute__((address_space(3))) void*)(lp), 16, 0, 0)

// ---------------- elementwise: f32 -> bf16 ----------------
__global__ void k_f2b(const float* __restrict__ in, u16* __restrict__ out, int n4) {
    int i = blockIdx.x * 256 + threadIdx.x;
    if (i >= n4) return;
    float4 v = ((const float4*)in)[i];
    ushort4 o;
    o.x = f2b(v.x); o.y = f2b(v.y); o.z = f2b(v.z); o.w = f2b(v.w);
    ((ushort4*)out)[i] = o;
}

// ---------------- weight transpose+convert: W[K,N] f32 -> Wt[N,K] bf16 ----------------
__global__ void k_wtrans(const float* __restrict__ W, u16* __restrict__ Wt, int K, int N) {
    __shared__ float t[32][33];
    int bx = blockIdx.x * 32, by = blockIdx.y * 32;
    int tx = threadIdx.x, ty = threadIdx.y;
    for (int i = 0; i < 32; i += 8)
        t[ty + i][tx] = W[(size_t)(by + ty + i) * N + bx + tx];
    __syncthreads();
    for (int i = 0; i < 32; i += 8)
        Wt[(size_t)(bx + ty + i) * K + by + tx] = f2b(t[tx][ty + i]);
}

// ---------------- fused QKV GEMM: [4096,1024]@[3072,1024]^T, epilogue writes Qa/Qc/Ka/Kc/Vt bf16 ----------------
__global__ __launch_bounds__(256) void gemm_qkv(const u16* __restrict__ A, const u16* __restrict__ Bt,
                                                const float* __restrict__ bq, const float* __restrict__ bk,
                                                const float* __restrict__ bv, const float* __restrict__ rel,
                                                u16* __restrict__ Qa, u16* __restrict__ Qc,
                                                u16* __restrict__ Ka, u16* __restrict__ Kc,
                                                u16* __restrict__ Vt) {
    __shared__ __align__(16) short lA[128 * 64];
    __shared__ __align__(16) short lB[128 * 64];
    const int tid = threadIdx.x, lane = tid & 63, w = tid >> 6;
    const int l15 = lane & 15, lg = lane >> 4;
    const int wr = w >> 1, wc = w & 1;
    const int m0 = blockIdx.y * 128, n0 = blockIdx.x * 128;
    const int KK = 1024;
    f32x4 acc[4][4] = {};

    for (int k0 = 0; k0 < KK; k0 += 64) {
        #pragma unroll
        for (int i = 0; i < 4; i++) {
            int chunk = w * 4 + i;
            int arow = m0 + chunk * 8 + (lane >> 3);
            GLDS(A + (size_t)arow * KK + k0 + (lane & 7) * 8, (short*)lA + chunk * 512);
            int brow = n0 + chunk * 8 + (lane >> 3);
            GLDS(Bt + (size_t)brow * KK + k0 + (lane & 7) * 8, (short*)lB + chunk * 512);
        }
        __syncthreads();
        #pragma unroll
        for (int ks = 0; ks < 2; ks++) {
            s16x8 af[4], bfr[4];
            #pragma unroll
            for (int m = 0; m < 4; m++)
                af[m] = *(const s16x8*)&lA[(wr * 64 + m * 16 + l15) * 64 + ks * 32 + lg * 8];
            #pragma unroll
            for (int n = 0; n < 4; n++)
                bfr[n] = *(const s16x8*)&lB[(wc * 64 + n * 16 + l15) * 64 + ks * 32 + lg * 8];
            #pragma unroll
            for (int m = 0; m < 4; m++)
                #pragma unroll
                for (int n = 0; n < 4; n++)
                    acc[m][n] = MFMA16(af[m], bfr[n], acc[m][n]);
        }
        __syncthreads();
    }
    const int rbase = m0 + wr * 64, cbase = n0 + wc * 64;
    const int seg = cbase >> 10;  // uniform per block (128-wide tiles)
    #pragma unroll
    for (int m = 0; m < 4; m++)
        #pragma unroll
        for (int n = 0; n < 4; n++) {
            int col = cbase + n * 16 + l15;
            int c1 = col & 1023, d = col & 63;
            int row0 = rbase + m * 16 + lg * 4;
            if (seg == 0) {
                float bb = bq[c1], r0 = rel[d], r1 = rel[64 + d];
                #pragma unroll
                for (int r = 0; r < 4; r++) {
                    float v = acc[m][n][r] + bb;
                    size_t o = (size_t)(row0 + r) * 1024 + c1;
                    Qa[o] = f2b(v + r0);
                    Qc[o] = f2b(v + r1);
                }
            } else if (seg == 1) {
                float bb = bk[c1], r0 = rel[d], r1 = rel[64 + d];
                #pragma unroll
                for (int r = 0; r < 4; r++) {
                    float v = acc[m][n][r] + bb;
                    size_t o = (size_t)(row0 + r) * 1024 + c1;
                    Ka[o] = f2b(v + r0);
                    Kc[o] = f2b(v + r1);
                }
            } else {
                float bb = bv[c1];
                #pragma unroll
                for (int r = 0; r < 4; r++) {
                    int row = row0 + r;
                    size_t o = (size_t)(row >> 6) * 65536 + (size_t)d * 1024 + (row & 63) * 16 + (c1 >> 6);
                    Vt[o] = f2b(acc[m][n][r] + bb);
                }
            }
        }
}

// ---------------- GEMM 128x128, EPI 1: bf16(relu(acc+bias)) ----------------
template <int EPI>
__global__ __launch_bounds__(256) void gemm_bt(const u16* __restrict__ A, const u16* __restrict__ Bt,
                                               void* __restrict__ Cv, int M, int N, int K,
                                               const float* __restrict__ bias) {
    __shared__ __align__(16) short lA[128 * 64];
    __shared__ __align__(16) short lB[128 * 64];
    const int tid = threadIdx.x, lane = tid & 63, w = tid >> 6;
    const int l15 = lane & 15, lg = lane >> 4;
    const int wr = w >> 1, wc = w & 1;
    const int m0 = blockIdx.y * 128, n0 = blockIdx.x * 128;
    f32x4 acc[4][4] = {};

    for (int k0 = 0; k0 < K; k0 += 64) {
        #pragma unroll
        for (int i = 0; i < 4; i++) {
            int chunk = w * 4 + i;
            int arow = m0 + chunk * 8 + (lane >> 3);
            GLDS(A + (size_t)arow * K + k0 + (lane & 7) * 8, (short*)lA + chunk * 512);
            int brow = n0 + chunk * 8 + (lane >> 3);
            GLDS(Bt + (size_t)brow * K + k0 + (lane & 7) * 8, (short*)lB + chunk * 512);
        }
        __syncthreads();
        #pragma unroll
        for (int ks = 0; ks < 2; ks++) {
            s16x8 af[4], bfr[4];
            #pragma unroll
            for (int m = 0; m < 4; m++)
                af[m] = *(const s16x8*)&lA[(wr * 64 + m * 16 + l15) * 64 + ks * 32 + lg * 8];
            #pragma unroll
            for (int n = 0; n < 4; n++)
                bfr[n] = *(const s16x8*)&lB[(wc * 64 + n * 16 + l15) * 64 + ks * 32 + lg * 8];
            #pragma unroll
            for (int m = 0; m < 4; m++)
                #pragma unroll
                for (int n = 0; n < 4; n++)
                    acc[m][n] = MFMA16(af[m], bfr[n], acc[m][n]);
        }
        __syncthreads();
    }
    const int rbase = m0 + wr * 64, cbase = n0 + wc * 64;
    #pragma unroll
    for (int m = 0; m < 4; m++)
        #pragma unroll
        for (int n = 0; n < 4; n++) {
            int col = cbase + n * 16 + l15;
            int row0 = rbase + m * 16 + lg * 4;
            u16* C = (u16*)Cv;
            float bv = bias[col];
            #pragma unroll
            for (int r = 0; r < 4; r++)
                C[(size_t)(row0 + r) * N + col] = f2b(fmaxf(acc[m][n][r] + bv, 0.f));
        }
}

// ---------------- GEMM 128x64 f32-out ----------------
__global__ __launch_bounds__(256) void gemm_bt64(const u16* __restrict__ A, const u16* __restrict__ Bt,
                                                 float* __restrict__ C, int M, int N, int K) {
    __shared__ __align__(16) short lA[128 * 64];
    __shared__ __align__(16) short lB[64 * 64];
    const int tid = threadIdx.x, lane = tid & 63, w = tid >> 6;
    const int l15 = lane & 15, lg = lane >> 4;
    const int m0 = blockIdx.y * 128, n0 = blockIdx.x * 64;
    f32x4 acc[2][4] = {};

    for (int k0 = 0; k0 < K; k0 += 64) {
        #pragma unroll
        for (int i = 0; i < 4; i++) {
            int chunk = w * 4 + i;
            int arow = m0 + chunk * 8 + (lane >> 3);
            GLDS(A + (size_t)arow * K + k0 + (lane & 7) * 8, (short*)lA + chunk * 512);
        }
        #pragma unroll
        for (int i = 0; i < 2; i++) {
            int chunk = w * 2 + i;
            int brow = n0 + chunk * 8 + (lane >> 3);
            GLDS(Bt + (size_t)brow * K + k0 + (lane & 7) * 8, (short*)lB + chunk * 512);
        }
        __syncthreads();
        #pragma unroll
        for (int ks = 0; ks < 2; ks++) {
            s16x8 af[2], bfr[4];
            #pragma unroll
            for (int m = 0; m < 2; m++)
                af[m] = *(const s16x8*)&lA[(w * 32 + m * 16 + l15) * 64 + ks * 32 + lg * 8];
            #pragma unroll
            for (int n = 0; n < 4; n++)
                bfr[n] = *(const s16x8*)&lB[(n * 16 + l15) * 64 + ks * 32 + lg * 8];
            #pragma unroll
            for (int m = 0; m < 2; m++)
                #pragma unroll
                for (int n = 0; n < 4; n++)
                    acc[m][n] = MFMA16(af[m], bfr[n], acc[m][n]);
        }
        __syncthreads();
    }
    #pragma unroll
    for (int m = 0; m < 2; m++)
        #pragma unroll
        for (int n = 0; n < 4; n++) {
            int col = n0 + n * 16 + l15;
            int row0 = m0 + w * 32 + m * 16 + lg * 4;
            #pragma unroll
            for (int r = 0; r < 4; r++)
                C[(size_t)(row0 + r) * N + col] = acc[m][n][r];
        }
}

// ---------------- stage A (both maps): S=QK^T, E=exp(S/8) -> linear bf16 blobs + denominators ----------------
// launch_bounds(256,2): cap 2 blocks/CU so the compiler has VGPR headroom to keep
// all of one iteration's loads in flight (R8 post-mortem: 88-VGPR budget serialized loads).
__global__ __launch_bounds__(256, 2) void k_qke2(const u16* __restrict__ Qa, const u16* __restrict__ Qc,
                                                 const u16* __restrict__ Ka, const u16* __restrict__ Kc,
                                                 u16* __restrict__ Ea, u16* __restrict__ Ec,
                                                 float* __restrict__ denA, float* __restrict__ denC) {
    const int bid = blockIdx.x;
    const int xcd = bid & 7, j = bid >> 3;
    const int g = xcd * 8 + (j & 7), qt = j >> 3;
    const int tid = threadIdx.x, lane = tid & 63, w = tid >> 6;
    const int l15 = lane & 15, lg = lane >> 4;
    __shared__ __align__(16) float lE[2][4][16][68];

    const int q0 = qt * 64 + w * 16;
    const size_t gQ = (size_t)g * 65536;
    const size_t ebase = ((((size_t)g * 16 + qt) * 4 + w) * 16384) + (size_t)lane * 8;
    const float scale = 0.125f;

    s16x8 qa[2], qc[2];
    #pragma unroll
    for (int ks = 0; ks < 2; ks++) {
        size_t off = gQ + (size_t)(q0 + l15) * 64 + ks * 32 + lg * 8;
        qa[ks] = *(const s16x8*)(Qa + off);
        qc[ks] = *(const s16x8*)(Qc + off);
    }

    float la[4] = {0.f, 0.f, 0.f, 0.f}, lc[4] = {0.f, 0.f, 0.f, 0.f};

    #pragma unroll 1
    for (int it = 0; it < 16; it++) {
        const int kb = it * 64;
        f32x4 sa[4] = {}, sc[4] = {};
        s16x8 kfa[8], kfc[8];
        #pragma unroll
        for (int ks = 0; ks < 2; ks++)
            #pragma unroll
            for (int n = 0; n < 4; n++) {
                size_t koff = gQ + (size_t)(kb + n * 16 + l15) * 64 + ks * 32 + lg * 8;
                kfa[ks * 4 + n] = *(const s16x8*)(Ka + koff);
                kfc[ks * 4 + n] = *(const s16x8*)(Kc + koff);
            }
        #pragma unroll
        for (int ks = 0; ks < 2; ks++)
            #pragma unroll
            for (int n = 0; n < 4; n++) {
                sa[n] = MFMA16(qa[ks], kfa[ks * 4 + n], sa[n]);
                sc[n] = MFMA16(qc[ks], kfc[ks * 4 + n], sc[n]);
            }
        #pragma unroll
        for (int n = 0; n < 4; n++)
            #pragma unroll
            for (int r = 0; r < 4; r++) {
                float ea = __expf(sa[n][r] * scale);
                float ec = __expf(sc[n][r] * scale);
                la[r] += ea;
                lc[r] += ec;
                lE[0][w][lg * 4 + r][n * 16 + l15] = ea;
                lE[1][w][lg * 4 + r][n * 16 + l15] = ec;
            }
        #pragma unroll
        for (int ks = 0; ks < 2; ks++) {
            const float* ep = &lE[0][w][l15][ks * 32 + lg * 8];
            float4 e0 = *(const float4*)ep, e1 = *(const float4*)(ep + 4);
            uint4 st;
            st.x = (u32)f2b(e0.x) | ((u32)f2b(e0.y) << 16);
            st.y = (u32)f2b(e0.z) | ((u32)f2b(e0.w) << 16);
            st.z = (u32)f2b(e1.x) | ((u32)f2b(e1.y) << 16);
            st.w = (u32)f2b(e1.z) | ((u32)f2b(e1.w) << 16);
            *(uint4*)(Ea + ebase + (size_t)it * 1024 + ks * 512) = st;
            const float* fp = &lE[1][w][l15][ks * 32 + lg * 8];
            float4 f0 = *(const float4*)fp, f1 = *(const float4*)(fp + 4);
            uint4 st2;
            st2.x = (u32)f2b(f0.x) | ((u32)f2b(f0.y) << 16);
            st2.y = (u32)f2b(f0.z) | ((u32)f2b(f0.w) << 16);
            st2.z = (u32)f2b(f1.x) | ((u32)f2b(f1.y) << 16);
            st2.w = (u32)f2b(f1.z) | ((u32)f2b(f1.w) << 16);
            *(uint4*)(Ec + ebase + (size_t)it * 1024 + ks * 512) = st2;
        }
    }
    #pragma unroll
    for (int r = 0; r < 4; r++)
        #pragma unroll
        for (int m = 8; m >= 1; m >>= 1) {
            la[r] += __shfl_xor(la[r], m);
            lc[r] += __shfl_xor(lc[r], m);
        }
    if (l15 == 0) {
        #pragma unroll
        for (int r = 0; r < 4; r++) {
            denA[g * 1024 + q0 + lg * 4 + r] = la[r];
            denC[g * 1024 + q0 + lg * 4 + r] = lc[r];
        }
    }
}

// ---------------- stage B (both maps): ctx = (Ea o Ma)@V/denA + (Ec o Mc)@V/denC ----------------
// Pure stream. launch_bounds(256,2): VGPR headroom so all 20 loads/iter stay in flight
// (the R8 kernel at 88 VGPR issued them serially -> 9500cy/iter).
__global__ __launch_bounds__(256, 2) void k_pv2(const u16* __restrict__ Ea, const u16* __restrict__ Ec,
                                                const u16* __restrict__ Vt,
                                                const float* __restrict__ adjm, const float* __restrict__ comm,
                                                const float* __restrict__ denA, const float* __restrict__ denC,
                                                u16* __restrict__ ctx) {
    const int bid = blockIdx.x;
    const int xcd = bid & 7, j = bid >> 3;
    const int g = xcd * 8 + (j & 7), qt = j >> 3;
    const int tid = threadIdx.x, lane = tid & 63, w = tid >> 6;
    const int l15 = lane & 15, lg = lane >> 4;

    const int q0 = qt * 64 + w * 16;
    const size_t gQ = (size_t)g * 65536;
    const size_t mroff = (size_t)g * 1048576 + (size_t)(q0 + l15) * 1024 + lg * 8;
    const float* __restrict__ mrow_a = adjm + mroff;
    const float* __restrict__ mrow_c = comm + mroff;
    const size_t ebase = ((((size_t)g * 16 + qt) * 4 + w) * 16384) + (size_t)lane * 8;

    f32x4 ca[4] = {}, cc[4] = {};

    #pragma unroll 2
    for (int it = 0; it < 16; it++) {
        const int kb = it * 64;
        s16x8 ea[2], ec[2], vf[8];
        float4 ma[4], mc[4];
        // masks first (HBM, longest latency), then E (HBM), then V (L2-warm)
        #pragma unroll
        for (int ks = 0; ks < 2; ks++) {
            ma[ks * 2 + 0] = *(const float4*)(mrow_a + kb + ks * 32);
            ma[ks * 2 + 1] = *(const float4*)(mrow_a + kb + ks * 32 + 4);
            mc[ks * 2 + 0] = *(const float4*)(mrow_c + kb + ks * 32);
            mc[ks * 2 + 1] = *(const float4*)(mrow_c + kb + ks * 32 + 4);
        }
        #pragma unroll
        for (int ks = 0; ks < 2; ks++) {
            ea[ks] = *(const s16x8*)(Ea + ebase + (size_t)it * 1024 + ks * 512);
            ec[ks] = *(const s16x8*)(Ec + ebase + (size_t)it * 1024 + ks * 512);
        }
        #pragma unroll
        for (int ks = 0; ks < 2; ks++)
            #pragma unroll
            for (int d = 0; d < 4; d++)
                vf[ks * 4 + d] = *(const s16x8*)(Vt + gQ + (size_t)(d * 16 + l15) * 1024 + kb + ks * 32 + lg * 8);
        #pragma unroll
        for (int ks = 0; ks < 2; ks++) {
            union { s16x8 v; u16 u[8]; } pa, pc;
            pa.u[0] = f2b(b2f((u16)ea[ks][0]) * ma[ks * 2].x);
            pa.u[1] = f2b(b2f((u16)ea[ks][1]) * ma[ks * 2].y);
            pa.u[2] = f2b(b2f((u16)ea[ks][2]) * ma[ks * 2].z);
            pa.u[3] = f2b(b2f((u16)ea[ks][3]) * ma[ks * 2].w);
            pa.u[4] = f2b(b2f((u16)ea[ks][4]) * ma[ks * 2 + 1].x);
            pa.u[5] = f2b(b2f((u16)ea[ks][5]) * ma[ks * 2 + 1].y);
            pa.u[6] = f2b(b2f((u16)ea[ks][6]) * ma[ks * 2 + 1].z);
            pa.u[7] = f2b(b2f((u16)ea[ks][7]) * ma[ks * 2 + 1].w);
            pc.u[0] = f2b(b2f((u16)ec[ks][0]) * mc[ks * 2].x);
            pc.u[1] = f2b(b2f((u16)ec[ks][1]) * mc[ks * 2].y);
            pc.u[2] = f2b(b2f((u16)ec[ks][2]) * mc[ks * 2].z);
            pc.u[3] = f2b(b2f((u16)ec[ks][3]) * mc[ks * 2].w);
            pc.u[4] = f2b(b2f((u16)ec[ks][4]) * mc[ks * 2 + 1].x);
            pc.u[5] = f2b(b2f((u16)ec[ks][5]) * mc[ks * 2 + 1].y);
            pc.u[6] = f2b(b2f((u16)ec[ks][6]) * mc[ks * 2 + 1].z);
            pc.u[7] = f2b(b2f((u16)ec[ks][7]) * mc[ks * 2 + 1].w);
            #pragma unroll
            for (int d = 0; d < 4; d++) {
                ca[d] = MFMA16(pa.v, vf[ks * 4 + d], ca[d]);
                cc[d] = MFMA16(pc.v, vf[ks * 4 + d], cc[d]);
            }
        }
    }
    float ila[4], ilc[4];
    #pragma unroll
    for (int r = 0; r < 4; r++) {
        ila[r] = 1.f / denA[g * 1024 + q0 + lg * 4 + r];
        ilc[r] = 1.f / denC[g * 1024 + q0 + lg * 4 + r];
    }
    #pragma unroll
    for (int r = 0; r < 4; r++) {
        int row = q0 + lg * 4 + r;
        #pragma unroll
        for (int d = 0; d < 4; d++)
            ctx[gQ + (size_t)row * 64 + d * 16 + l15] = f2b(ca[d][r] * ila[r] + cc[d][r] * ilc[r]);
    }
}

// ---------------- row LayerNorm ----------------
__global__ __launch_bounds__(256) void k_ln(const float* __restrict__ a, const float* __restrict__ bias,
                                            const float* __restrict__ resid, const float* __restrict__ gamma,
                                            const float* __restrict__ beta, float* __restrict__ out,
                                            u16* __restrict__ outb) {
    const int row = blockIdx.x, tid = threadIdx.x;
    const size_t base = (size_t)row * 1024 + tid * 4;
    float4 av = *(const float4*)(a + base);
    float4 rv = *(const float4*)(resid + base);
    float4 bv = *(const float4*)(bias + tid * 4);
    float t0 = av.x + rv.x + bv.x, t1 = av.y + rv.y + bv.y;
    float t2 = av.z + rv.z + bv.z, t3 = av.w + rv.w + bv.w;
    __shared__ float red[4];
    float s = t0 + t1 + t2 + t3;
    #pragma unroll
    for (int m = 32; m >= 1; m >>= 1) s += __shfl_xor(s, m);
    int w = tid >> 6;
    if ((tid & 63) == 0) red[w] = s;
    __syncthreads();
    float mean = (red[0] + red[1] + red[2] + red[3]) * (1.f / 1024.f);
    float d0 = t0 - mean, d1 = t1 - mean, d2 = t2 - mean, d3 = t3 - mean;
    float q = d0 * d0 + d1 * d1 + d2 * d2 + d3 * d3;
    __syncthreads();
    #pragma unroll
    for (int m = 32; m >= 1; m >>= 1) q += __shfl_xor(q, m);
    if ((tid & 63) == 0) red[w] = q;
    __syncthreads();
    float var = (red[0] + red[1] + red[2] + red[3]) * (1.f / 1024.f);
    float rs = rsqrtf(var + 1e-5f);
    float4 gv = *(const float4*)(gamma + tid * 4);
    float4 bev = *(const float4*)(beta + tid * 4);
    float o0 = d0 * rs * gv.x + bev.x, o1 = d1 * rs * gv.y + bev.y;
    float o2 = d2 * rs * gv.z + bev.z, o3 = d3 * rs * gv.w + bev.w;
    *(float4*)(out + base) = make_float4(o0, o1, o2, o3);
    if (outb) {
        ushort4 ob;
        ob.x = f2b(o0); ob.y = f2b(o1); ob.z = f2b(o2); ob.w = f2b(o3);
        *(ushort4*)(outb + base) = ob;
    }
}

extern "C" void kernel_launch(void* const* d_in, const int* in_sizes, int n_in,
                              void* d_out, int out_size, void* d_ws, size_t ws_size,
                              hipStream_t stream) {
    const float* x    = (const float*)d_in[0];
    const float* adjm = (const float*)d_in[1];
    const float* comm = (const float*)d_in[2];
    const float* rel  = (const float*)d_in[3];
    const float* Wq   = (const float*)d_in[4];
    const float* bq   = (const float*)d_in[5];
    const float* Wk   = (const float*)d_in[6];
    const float* bk   = (const float*)d_in[7];
    const float* Wv   = (const float*)d_in[8];
    const float* bv   = (const float*)d_in[9];
    const float* Wo   = (const float*)d_in[10];
    const float* bo   = (const float*)d_in[11];
    const float* g1   = (const float*)d_in[12];
    const float* be1  = (const float*)d_in[13];
    const float* W1   = (const float*)d_in[14];
    const float* b1   = (const float*)d_in[15];
    const float* W2   = (const float*)d_in[16];
    const float* b2   = (const float*)d_in[17];
    const float* g2   = (const float*)d_in[18];
    const float* be2  = (const float*)d_in[19];
    float* out = (float*)d_out;

    char* ws = (char*)d_ws;
    const size_t MB = 1048576;
    u16*   xb    = (u16*)(ws + 0 * MB);      // 8 MiB (dead after gemm_qkv)
    u16*   Wqkvt = (u16*)(ws + 8 * MB);      // 6 MiB
    u16*   Wot   = (u16*)(ws + 14 * MB);     // 2 MiB
    u16*   W1t   = (u16*)(ws + 16 * MB);     // 8 MiB
    u16*   W2t   = (u16*)(ws + 24 * MB);     // 8 MiB (live through FFN2)
    u16*   Qab   = (u16*)(ws + 32 * MB);     // 8 MiB each [32,72)
    u16*   Qcb   = (u16*)(ws + 40 * MB);
    u16*   Kab   = (u16*)(ws + 48 * MB);
    u16*   Kcb   = (u16*)(ws + 56 * MB);
    u16*   Vtb   = (u16*)(ws + 64 * MB);
    u16*   Eab   = (u16*)(ws + 72 * MB);     // 128 MiB [72,200)
    u16*   Ecb   = (u16*)(ws + 200 * MB);    // 128 MiB [200,328)
    float* denA  = (float*)(ws + 328 * MB);  // 256 KiB
    float* denC  = (float*)(ws + 329 * MB);  // 256 KiB
    u16*   ctx   = (u16*)(ws + 330 * MB);    // 8 MiB (dead after Wo gemm)
    float* ctxWo = (float*)(ws + 32 * MB);   // reuse Qab/Qcb (dead after attn)
    float* out1  = (float*)(ws + 48 * MB);   // reuse Kab/Kcb (live to LN2)
    u16*   out1b = (u16*)(ws + 64 * MB);     // reuse Vtb
    u16*   rb    = (u16*)(ws + 72 * MB);     // 32 MiB reuse Eab (dead after k_pv2)
    float* ff2   = (float*)(ws + 0 * MB);    // 16 MiB reuse xb+weights (dead)

    dim3 tb(32, 8);
    // 1. casts / weight prep
    k_f2b<<<4096, 256, 0, stream>>>(x, xb, 1048576);
    k_wtrans<<<dim3(32, 32), tb, 0, stream>>>(Wq, Wqkvt, 1024, 1024);
    k_wtrans<<<dim3(32, 32), tb, 0, stream>>>(Wk, Wqkvt + 1024 * 1024, 1024, 1024);
    k_wtrans<<<dim3(32, 32), tb, 0, stream>>>(Wv, Wqkvt + 2 * 1024 * 1024, 1024, 1024);
    k_wtrans<<<dim3(32, 32), tb, 0, stream>>>(Wo, Wot, 1024, 1024);
    k_wtrans<<<dim3(128, 32), tb, 0, stream>>>(W1, W1t, 1024, 4096);
    k_wtrans<<<dim3(32, 128), tb, 0, stream>>>(W2, W2t, 4096, 1024);
    // 2. fused QKV projection + epilogues (Qa/Qc/Ka/Kc flat, Vt transposed)
    gemm_qkv<<<dim3(24, 32), 256, 0, stream>>>(xb, Wqkvt, bq, bk, bv, rel,
                                               Qab, Qcb, Kab, Kcb, Vtb);
    // 3. attention: merged two-stage (streaming structure, VGPR-unthrottled)
    k_qke2<<<1024, 256, 0, stream>>>(Qab, Qcb, Kab, Kcb, Eab, Ecb, denA, denC);
    k_pv2<<<1024, 256, 0, stream>>>(Eab, Ecb, Vtb, adjm, comm, denA, denC, ctx);
    // 4. output projection + LN1
    gemm_bt64<<<dim3(16, 32), 256, 0, stream>>>(ctx, Wot, ctxWo, 4096, 1024, 1024);
    k_ln<<<4096, 256, 0, stream>>>(ctxWo, bo, x, g1, be1, out1, out1b);
    // 5. FFN
    gemm_bt<1><<<dim3(32, 32), 256, 0, stream>>>(out1b, W1t, rb, 4096, 4096, 1024, b1);
    gemm_bt64<<<dim3(16, 32), 256, 0, stream>>>(rb, W2t, ff2, 4096, 1024, 4096);
    // 6. LN2 -> final output
    k_ln<<<4096, 256, 0, stream>>>(ff2, b2, out1, g2, be2, out, nullptr);
}

// Round 10
// 646.640 us; speedup vs baseline: 1.0378x; 1.0115x over previous
//
#include <hip/hip_runtime.h>
#include <hip/hip_bf16.h>

typedef __attribute__((ext_vector_type(8))) short s16x8;
typedef __attribute__((ext_vector_type(4))) float f32x4;
typedef unsigned short u16;
typedef unsigned int u32;

__device__ __forceinline__ u16 f2b(float f) {
    u32 u = __float_as_uint(f);
    u32 r = (u + 0x7fffu + ((u >> 16) & 1u)) >> 16;  // RNE bf16
    return (u16)r;
}
__device__ __forceinline__ float b2f(u16 b) {
    return __uint_as_float(((u32)b) << 16);
}

#define MFMA16(a, b, c) __builtin_amdgcn_mfma_f32_16x16x32_bf16(a, b, c, 0, 0, 0)
#define GLDS(gp, lp)                                                              \
    __builtin_amdgcn_global_load_lds((const __attribute__((address_space(1))) void*)(gp), \
                                     (__attribute__((address_space(3))) void*)(lp), 16, 0, 0)

// ---------------- elementwise: f32 -> bf16 ----------------
__global__ void k_f2b(const float* __restrict__ in, u16* __restrict__ out, int n4) {
    int i = blockIdx.x * 256 + threadIdx.x;
    if (i >= n4) return;
    float4 v = ((const float4*)in)[i];
    ushort4 o;
    o.x = f2b(v.x); o.y = f2b(v.y); o.z = f2b(v.z); o.w = f2b(v.w);
    ((ushort4*)out)[i] = o;
}

// ---------------- weight transpose+convert: W[K,N] f32 -> Wt[N,K] bf16 ----------------
__global__ void k_wtrans(const float* __restrict__ W, u16* __restrict__ Wt, int K, int N) {
    __shared__ float t[32][33];
    int bx = blockIdx.x * 32, by = blockIdx.y * 32;
    int tx = threadIdx.x, ty = threadIdx.y;
    for (int i = 0; i < 32; i += 8)
        t[ty + i][tx] = W[(size_t)(by + ty + i) * N + bx + tx];
    __syncthreads();
    for (int i = 0; i < 32; i += 8)
        Wt[(size_t)(bx + ty + i) * K + by + tx] = f2b(t[tx][ty + i]);
}

// ---------------- fused QKV GEMM: [4096,1024]@[3072,1024]^T, epilogue writes Qa/Qc/Ka/Kc/Vt bf16 ----------------
__global__ __launch_bounds__(256) void gemm_qkv(const u16* __restrict__ A, const u16* __restrict__ Bt,
                                                const float* __restrict__ bq, const float* __restrict__ bk,
                                                const float* __restrict__ bv, const float* __restrict__ rel,
                                                u16* __restrict__ Qa, u16* __restrict__ Qc,
                                                u16* __restrict__ Ka, u16* __restrict__ Kc,
                                                u16* __restrict__ Vt) {
    __shared__ __align__(16) short lA[128 * 64];
    __shared__ __align__(16) short lB[128 * 64];
    const int tid = threadIdx.x, lane = tid & 63, w = tid >> 6;
    const int l15 = lane & 15, lg = lane >> 4;
    const int wr = w >> 1, wc = w & 1;
    const int m0 = blockIdx.y * 128, n0 = blockIdx.x * 128;
    const int KK = 1024;
    f32x4 acc[4][4] = {};

    for (int k0 = 0; k0 < KK; k0 += 64) {
        #pragma unroll
        for (int i = 0; i < 4; i++) {
            int chunk = w * 4 + i;
            int arow = m0 + chunk * 8 + (lane >> 3);
            GLDS(A + (size_t)arow * KK + k0 + (lane & 7) * 8, (short*)lA + chunk * 512);
            int brow = n0 + chunk * 8 + (lane >> 3);
            GLDS(Bt + (size_t)brow * KK + k0 + (lane & 7) * 8, (short*)lB + chunk * 512);
        }
        __syncthreads();
        #pragma unroll
        for (int ks = 0; ks < 2; ks++) {
            s16x8 af[4], bfr[4];
            #pragma unroll
            for (int m = 0; m < 4; m++)
                af[m] = *(const s16x8*)&lA[(wr * 64 + m * 16 + l15) * 64 + ks * 32 + lg * 8];
            #pragma unroll
            for (int n = 0; n < 4; n++)
                bfr[n] = *(const s16x8*)&lB[(wc * 64 + n * 16 + l15) * 64 + ks * 32 + lg * 8];
            #pragma unroll
            for (int m = 0; m < 4; m++)
                #pragma unroll
                for (int n = 0; n < 4; n++)
                    acc[m][n] = MFMA16(af[m], bfr[n], acc[m][n]);
        }
        __syncthreads();
    }
    const int rbase = m0 + wr * 64, cbase = n0 + wc * 64;
    const int seg = cbase >> 10;  // uniform per block (128-wide tiles)
    #pragma unroll
    for (int m = 0; m < 4; m++)
        #pragma unroll
        for (int n = 0; n < 4; n++) {
            int col = cbase + n * 16 + l15;
            int c1 = col & 1023, d = col & 63;
            int row0 = rbase + m * 16 + lg * 4;
            if (seg == 0) {
                float bb = bq[c1], r0 = rel[d], r1 = rel[64 + d];
                #pragma unroll
                for (int r = 0; r < 4; r++) {
                    float v = acc[m][n][r] + bb;
                    size_t o = (size_t)(row0 + r) * 1024 + c1;
                    Qa[o] = f2b(v + r0);
                    Qc[o] = f2b(v + r1);
                }
            } else if (seg == 1) {
                float bb = bk[c1], r0 = rel[d], r1 = rel[64 + d];
                #pragma unroll
                for (int r = 0; r < 4; r++) {
                    float v = acc[m][n][r] + bb;
                    size_t o = (size_t)(row0 + r) * 1024 + c1;
                    Ka[o] = f2b(v + r0);
                    Kc[o] = f2b(v + r1);
                }
            } else {
                float bb = bv[c1];
                #pragma unroll
                for (int r = 0; r < 4; r++) {
                    int row = row0 + r;
                    size_t o = (size_t)(row >> 6) * 65536 + (size_t)d * 1024 + (row & 63) * 16 + (c1 >> 6);
                    Vt[o] = f2b(acc[m][n][r] + bb);
                }
            }
        }
}

// ---------------- GEMM 128x128, EPI 1: bf16(relu(acc+bias)) ----------------
template <int EPI>
__global__ __launch_bounds__(256) void gemm_bt(const u16* __restrict__ A, const u16* __restrict__ Bt,
                                               void* __restrict__ Cv, int M, int N, int K,
                                               const float* __restrict__ bias) {
    __shared__ __align__(16) short lA[128 * 64];
    __shared__ __align__(16) short lB[128 * 64];
    const int tid = threadIdx.x, lane = tid & 63, w = tid >> 6;
    const int l15 = lane & 15, lg = lane >> 4;
    const int wr = w >> 1, wc = w & 1;
    const int m0 = blockIdx.y * 128, n0 = blockIdx.x * 128;
    f32x4 acc[4][4] = {};

    for (int k0 = 0; k0 < K; k0 += 64) {
        #pragma unroll
        for (int i = 0; i < 4; i++) {
            int chunk = w * 4 + i;
            int arow = m0 + chunk * 8 + (lane >> 3);
            GLDS(A + (size_t)arow * K + k0 + (lane & 7) * 8, (short*)lA + chunk * 512);
            int brow = n0 + chunk * 8 + (lane >> 3);
            GLDS(Bt + (size_t)brow * K + k0 + (lane & 7) * 8, (short*)lB + chunk * 512);
        }
        __syncthreads();
        #pragma unroll
        for (int ks = 0; ks < 2; ks++) {
            s16x8 af[4], bfr[4];
            #pragma unroll
            for (int m = 0; m < 4; m++)
                af[m] = *(const s16x8*)&lA[(wr * 64 + m * 16 + l15) * 64 + ks * 32 + lg * 8];
            #pragma unroll
            for (int n = 0; n < 4; n++)
                bfr[n] = *(const s16x8*)&lB[(wc * 64 + n * 16 + l15) * 64 + ks * 32 + lg * 8];
            #pragma unroll
            for (int m = 0; m < 4; m++)
                #pragma unroll
                for (int n = 0; n < 4; n++)
                    acc[m][n] = MFMA16(af[m], bfr[n], acc[m][n]);
        }
        __syncthreads();
    }
    const int rbase = m0 + wr * 64, cbase = n0 + wc * 64;
    #pragma unroll
    for (int m = 0; m < 4; m++)
        #pragma unroll
        for (int n = 0; n < 4; n++) {
            int col = cbase + n * 16 + l15;
            int row0 = rbase + m * 16 + lg * 4;
            u16* C = (u16*)Cv;
            float bv = bias[col];
            #pragma unroll
            for (int r = 0; r < 4; r++)
                C[(size_t)(row0 + r) * N + col] = f2b(fmaxf(acc[m][n][r] + bv, 0.f));
        }
}

// ---------------- GEMM 128x64 f32-out ----------------
__global__ __launch_bounds__(256) void gemm_bt64(const u16* __restrict__ A, const u16* __restrict__ Bt,
                                                 float* __restrict__ C, int M, int N, int K) {
    __shared__ __align__(16) short lA[128 * 64];
    __shared__ __align__(16) short lB[64 * 64];
    const int tid = threadIdx.x, lane = tid & 63, w = tid >> 6;
    const int l15 = lane & 15, lg = lane >> 4;
    const int m0 = blockIdx.y * 128, n0 = blockIdx.x * 64;
    f32x4 acc[2][4] = {};

    for (int k0 = 0; k0 < K; k0 += 64) {
        #pragma unroll
        for (int i = 0; i < 4; i++) {
            int chunk = w * 4 + i;
            int arow = m0 + chunk * 8 + (lane >> 3);
            GLDS(A + (size_t)arow * K + k0 + (lane & 7) * 8, (short*)lA + chunk * 512);
        }
        #pragma unroll
        for (int i = 0; i < 2; i++) {
            int chunk = w * 2 + i;
            int brow = n0 + chunk * 8 + (lane >> 3);
            GLDS(Bt + (size_t)brow * K + k0 + (lane & 7) * 8, (short*)lB + chunk * 512);
        }
        __syncthreads();
        #pragma unroll
        for (int ks = 0; ks < 2; ks++) {
            s16x8 af[2], bfr[4];
            #pragma unroll
            for (int m = 0; m < 2; m++)
                af[m] = *(const s16x8*)&lA[(w * 32 + m * 16 + l15) * 64 + ks * 32 + lg * 8];
            #pragma unroll
            for (int n = 0; n < 4; n++)
                bfr[n] = *(const s16x8*)&lB[(n * 16 + l15) * 64 + ks * 32 + lg * 8];
            #pragma unroll
            for (int m = 0; m < 2; m++)
                #pragma unroll
                for (int n = 0; n < 4; n++)
                    acc[m][n] = MFMA16(af[m], bfr[n], acc[m][n]);
        }
        __syncthreads();
    }
    #pragma unroll
    for (int m = 0; m < 2; m++)
        #pragma unroll
        for (int n = 0; n < 4; n++) {
            int col = n0 + n * 16 + l15;
            int row0 = m0 + w * 32 + m * 16 + lg * 4;
            #pragma unroll
            for (int r = 0; r < 4; r++)
                C[(size_t)(row0 + r) * N + col] = acc[m][n][r];
        }
}

// ---------------- stage A (both maps, k-split x2): E=exp(QK^T/8) blobs + PARTIAL denominators ----------------
// grid 2048: bid -> (xcd, g, qt, half). Half h handles k-tiles h*8..h*8+7, writes its E
// segment (disjoint) and den[h] partials. Doubles wave count -> occupancy ~2x (R9: grid-limited 45%).
__global__ __launch_bounds__(256, 2) void k_qke2(const u16* __restrict__ Qa, const u16* __restrict__ Qc,
                                                 const u16* __restrict__ Ka, const u16* __restrict__ Kc,
                                                 u16* __restrict__ Ea, u16* __restrict__ Ec,
                                                 float* __restrict__ denA2, float* __restrict__ denC2) {
    const int bid = blockIdx.x;
    const int xcd = bid & 7, j = bid >> 3;           // j: 0..255
    const int g = xcd * 8 + (j & 7);
    const int rest = j >> 3;                         // 0..31
    const int qt = rest & 15, h = rest >> 4;         // half: 0 or 1
    const int tid = threadIdx.x, lane = tid & 63, w = tid >> 6;
    const int l15 = lane & 15, lg = lane >> 4;
    __shared__ __align__(16) float lE[2][4][16][68];

    const int q0 = qt * 64 + w * 16;
    const size_t gQ = (size_t)g * 65536;
    const size_t ebase = ((((size_t)g * 16 + qt) * 4 + w) * 16384) + (size_t)lane * 8;
    const float scale = 0.125f;

    s16x8 qa[2], qc[2];
    #pragma unroll
    for (int ks = 0; ks < 2; ks++) {
        size_t off = gQ + (size_t)(q0 + l15) * 64 + ks * 32 + lg * 8;
        qa[ks] = *(const s16x8*)(Qa + off);
        qc[ks] = *(const s16x8*)(Qc + off);
    }

    float la[4] = {0.f, 0.f, 0.f, 0.f}, lc[4] = {0.f, 0.f, 0.f, 0.f};

    #pragma unroll 1
    for (int it = h * 8; it < h * 8 + 8; it++) {
        const int kb = it * 64;
        f32x4 sa[4] = {}, sc[4] = {};
        s16x8 kfa[8], kfc[8];
        #pragma unroll
        for (int ks = 0; ks < 2; ks++)
            #pragma unroll
            for (int n = 0; n < 4; n++) {
                size_t koff = gQ + (size_t)(kb + n * 16 + l15) * 64 + ks * 32 + lg * 8;
                kfa[ks * 4 + n] = *(const s16x8*)(Ka + koff);
                kfc[ks * 4 + n] = *(const s16x8*)(Kc + koff);
            }
        #pragma unroll
        for (int ks = 0; ks < 2; ks++)
            #pragma unroll
            for (int n = 0; n < 4; n++) {
                sa[n] = MFMA16(qa[ks], kfa[ks * 4 + n], sa[n]);
                sc[n] = MFMA16(qc[ks], kfc[ks * 4 + n], sc[n]);
            }
        #pragma unroll
        for (int n = 0; n < 4; n++)
            #pragma unroll
            for (int r = 0; r < 4; r++) {
                float ea = __expf(sa[n][r] * scale);
                float ec = __expf(sc[n][r] * scale);
                la[r] += ea;
                lc[r] += ec;
                lE[0][w][lg * 4 + r][n * 16 + l15] = ea;
                lE[1][w][lg * 4 + r][n * 16 + l15] = ec;
            }
        #pragma unroll
        for (int ks = 0; ks < 2; ks++) {
            const float* ep = &lE[0][w][l15][ks * 32 + lg * 8];
            float4 e0 = *(const float4*)ep, e1 = *(const float4*)(ep + 4);
            uint4 st;
            st.x = (u32)f2b(e0.x) | ((u32)f2b(e0.y) << 16);
            st.y = (u32)f2b(e0.z) | ((u32)f2b(e0.w) << 16);
            st.z = (u32)f2b(e1.x) | ((u32)f2b(e1.y) << 16);
            st.w = (u32)f2b(e1.z) | ((u32)f2b(e1.w) << 16);
            *(uint4*)(Ea + ebase + (size_t)it * 1024 + ks * 512) = st;
            const float* fp = &lE[1][w][l15][ks * 32 + lg * 8];
            float4 f0 = *(const float4*)fp, f1 = *(const float4*)(fp + 4);
            uint4 st2;
            st2.x = (u32)f2b(f0.x) | ((u32)f2b(f0.y) << 16);
            st2.y = (u32)f2b(f0.z) | ((u32)f2b(f0.w) << 16);
            st2.z = (u32)f2b(f1.x) | ((u32)f2b(f1.y) << 16);
            st2.w = (u32)f2b(f1.z) | ((u32)f2b(f1.w) << 16);
            *(uint4*)(Ec + ebase + (size_t)it * 1024 + ks * 512) = st2;
        }
    }
    #pragma unroll
    for (int r = 0; r < 4; r++)
        #pragma unroll
        for (int m = 8; m >= 1; m >>= 1) {
            la[r] += __shfl_xor(la[r], m);
            lc[r] += __shfl_xor(lc[r], m);
        }
    if (l15 == 0) {
        #pragma unroll
        for (int r = 0; r < 4; r++) {
            denA2[h * 65536 + g * 1024 + q0 + lg * 4 + r] = la[r];
            denC2[h * 65536 + g * 1024 + q0 + lg * 4 + r] = lc[r];
        }
    }
}

// ---------------- stage B (both maps, k-split x2): normalized f32 partials per half ----------------
__global__ __launch_bounds__(256, 2) void k_pv2(const u16* __restrict__ Ea, const u16* __restrict__ Ec,
                                                const u16* __restrict__ Vt,
                                                const float* __restrict__ adjm, const float* __restrict__ comm,
                                                const float* __restrict__ denA2, const float* __restrict__ denC2,
                                                float* __restrict__ ctxP) {
    const int bid = blockIdx.x;
    const int xcd = bid & 7, j = bid >> 3;
    const int g = xcd * 8 + (j & 7);
    const int rest = j >> 3;
    const int qt = rest & 15, h = rest >> 4;
    const int tid = threadIdx.x, lane = tid & 63, w = tid >> 6;
    const int l15 = lane & 15, lg = lane >> 4;

    const int q0 = qt * 64 + w * 16;
    const size_t gQ = (size_t)g * 65536;
    const size_t mroff = (size_t)g * 1048576 + (size_t)(q0 + l15) * 1024 + lg * 8;
    const float* __restrict__ mrow_a = adjm + mroff;
    const float* __restrict__ mrow_c = comm + mroff;
    const size_t ebase = ((((size_t)g * 16 + qt) * 4 + w) * 16384) + (size_t)lane * 8;

    f32x4 ca[4] = {}, cc[4] = {};

    #pragma unroll 2
    for (int it = h * 8; it < h * 8 + 8; it++) {
        const int kb = it * 64;
        s16x8 ea[2], ec[2], vf[8];
        float4 ma[4], mc[4];
        // masks first (HBM, longest latency), then E (HBM), then V (L2-warm)
        #pragma unroll
        for (int ks = 0; ks < 2; ks++) {
            ma[ks * 2 + 0] = *(const float4*)(mrow_a + kb + ks * 32);
            ma[ks * 2 + 1] = *(const float4*)(mrow_a + kb + ks * 32 + 4);
            mc[ks * 2 + 0] = *(const float4*)(mrow_c + kb + ks * 32);
            mc[ks * 2 + 1] = *(const float4*)(mrow_c + kb + ks * 32 + 4);
        }
        #pragma unroll
        for (int ks = 0; ks < 2; ks++) {
            ea[ks] = *(const s16x8*)(Ea + ebase + (size_t)it * 1024 + ks * 512);
            ec[ks] = *(const s16x8*)(Ec + ebase + (size_t)it * 1024 + ks * 512);
        }
        #pragma unroll
        for (int ks = 0; ks < 2; ks++)
            #pragma unroll
            for (int d = 0; d < 4; d++)
                vf[ks * 4 + d] = *(const s16x8*)(Vt + gQ + (size_t)(d * 16 + l15) * 1024 + kb + ks * 32 + lg * 8);
        #pragma unroll
        for (int ks = 0; ks < 2; ks++) {
            union { s16x8 v; u16 u[8]; } pa, pc;
            pa.u[0] = f2b(b2f((u16)ea[ks][0]) * ma[ks * 2].x);
            pa.u[1] = f2b(b2f((u16)ea[ks][1]) * ma[ks * 2].y);
            pa.u[2] = f2b(b2f((u16)ea[ks][2]) * ma[ks * 2].z);
            pa.u[3] = f2b(b2f((u16)ea[ks][3]) * ma[ks * 2].w);
            pa.u[4] = f2b(b2f((u16)ea[ks][4]) * ma[ks * 2 + 1].x);
            pa.u[5] = f2b(b2f((u16)ea[ks][5]) * ma[ks * 2 + 1].y);
            pa.u[6] = f2b(b2f((u16)ea[ks][6]) * ma[ks * 2 + 1].z);
            pa.u[7] = f2b(b2f((u16)ea[ks][7]) * ma[ks * 2 + 1].w);
            pc.u[0] = f2b(b2f((u16)ec[ks][0]) * mc[ks * 2].x);
            pc.u[1] = f2b(b2f((u16)ec[ks][1]) * mc[ks * 2].y);
            pc.u[2] = f2b(b2f((u16)ec[ks][2]) * mc[ks * 2].z);
            pc.u[3] = f2b(b2f((u16)ec[ks][3]) * mc[ks * 2].w);
            pc.u[4] = f2b(b2f((u16)ec[ks][4]) * mc[ks * 2 + 1].x);
            pc.u[5] = f2b(b2f((u16)ec[ks][5]) * mc[ks * 2 + 1].y);
            pc.u[6] = f2b(b2f((u16)ec[ks][6]) * mc[ks * 2 + 1].z);
            pc.u[7] = f2b(b2f((u16)ec[ks][7]) * mc[ks * 2 + 1].w);
            #pragma unroll
            for (int d = 0; d < 4; d++) {
                ca[d] = MFMA16(pa.v, vf[ks * 4 + d], ca[d]);
                cc[d] = MFMA16(pc.v, vf[ks * 4 + d], cc[d]);
            }
        }
    }
    float ila[4], ilc[4];
    #pragma unroll
    for (int r = 0; r < 4; r++) {
        int idx = g * 1024 + q0 + lg * 4 + r;
        ila[r] = 1.f / (denA2[idx] + denA2[65536 + idx]);
        ilc[r] = 1.f / (denC2[idx] + denC2[65536 + idx]);
    }
    #pragma unroll
    for (int r = 0; r < 4; r++) {
        int row = q0 + lg * 4 + r;
        #pragma unroll
        for (int d = 0; d < 4; d++)
            ctxP[(size_t)h * 4194304 + gQ + (size_t)row * 64 + d * 16 + l15] =
                ca[d][r] * ila[r] + cc[d][r] * ilc[r];
    }
}

// ---------------- combine the two k-halves -> bf16 ctx ----------------
__global__ void k_comb2(const float* __restrict__ P, u16* __restrict__ out, int n4) {
    int i = blockIdx.x * 256 + threadIdx.x;
    if (i >= n4) return;
    float4 a = ((const float4*)P)[i];
    float4 c = ((const float4*)(P + 4194304))[i];
    ushort4 o;
    o.x = f2b(a.x + c.x); o.y = f2b(a.y + c.y);
    o.z = f2b(a.z + c.z); o.w = f2b(a.w + c.w);
    ((ushort4*)out)[i] = o;
}

// ---------------- row LayerNorm ----------------
__global__ __launch_bounds__(256) void k_ln(const float* __restrict__ a, const float* __restrict__ bias,
                                            const float* __restrict__ resid, const float* __restrict__ gamma,
                                            const float* __restrict__ beta, float* __restrict__ out,
                                            u16* __restrict__ outb) {
    const int row = blockIdx.x, tid = threadIdx.x;
    const size_t base = (size_t)row * 1024 + tid * 4;
    float4 av = *(const float4*)(a + base);
    float4 rv = *(const float4*)(resid + base);
    float4 bv = *(const float4*)(bias + tid * 4);
    float t0 = av.x + rv.x + bv.x, t1 = av.y + rv.y + bv.y;
    float t2 = av.z + rv.z + bv.z, t3 = av.w + rv.w + bv.w;
    __shared__ float red[4];
    float s = t0 + t1 + t2 + t3;
    #pragma unroll
    for (int m = 32; m >= 1; m >>= 1) s += __shfl_xor(s, m);
    int w = tid >> 6;
    if ((tid & 63) == 0) red[w] = s;
    __syncthreads();
    float mean = (red[0] + red[1] + red[2] + red[3]) * (1.f / 1024.f);
    float d0 = t0 - mean, d1 = t1 - mean, d2 = t2 - mean, d3 = t3 - mean;
    float q = d0 * d0 + d1 * d1 + d2 * d2 + d3 * d3;
    __syncthreads();
    #pragma unroll
    for (int m = 32; m >= 1; m >>= 1) q += __shfl_xor(q, m);
    if ((tid & 63) == 0) red[w] = q;
    __syncthreads();
    float var = (red[0] + red[1] + red[2] + red[3]) * (1.f / 1024.f);
    float rs = rsqrtf(var + 1e-5f);
    float4 gv = *(const float4*)(gamma + tid * 4);
    float4 bev = *(const float4*)(beta + tid * 4);
    float o0 = d0 * rs * gv.x + bev.x, o1 = d1 * rs * gv.y + bev.y;
    float o2 = d2 * rs * gv.z + bev.z, o3 = d3 * rs * gv.w + bev.w;
    *(float4*)(out + base) = make_float4(o0, o1, o2, o3);
    if (outb) {
        ushort4 ob;
        ob.x = f2b(o0); ob.y = f2b(o1); ob.z = f2b(o2); ob.w = f2b(o3);
        *(ushort4*)(outb + base) = ob;
    }
}

extern "C" void kernel_launch(void* const* d_in, const int* in_sizes, int n_in,
                              void* d_out, int out_size, void* d_ws, size_t ws_size,
                              hipStream_t stream) {
    const float* x    = (const float*)d_in[0];
    const float* adjm = (const float*)d_in[1];
    const float* comm = (const float*)d_in[2];
    const float* rel  = (const float*)d_in[3];
    const float* Wq   = (const float*)d_in[4];
    const float* bq   = (const float*)d_in[5];
    const float* Wk   = (const float*)d_in[6];
    const float* bk   = (const float*)d_in[7];
    const float* Wv   = (const float*)d_in[8];
    const float* bv   = (const float*)d_in[9];
    const float* Wo   = (const float*)d_in[10];
    const float* bo   = (const float*)d_in[11];
    const float* g1   = (const float*)d_in[12];
    const float* be1  = (const float*)d_in[13];
    const float* W1   = (const float*)d_in[14];
    const float* b1   = (const float*)d_in[15];
    const float* W2   = (const float*)d_in[16];
    const float* b2   = (const float*)d_in[17];
    const float* g2   = (const float*)d_in[18];
    const float* be2  = (const float*)d_in[19];
    float* out = (float*)d_out;

    char* ws = (char*)d_ws;
    const size_t MB = 1048576;
    u16*   xb    = (u16*)(ws + 0 * MB);      // 8 MiB (dead after gemm_qkv)
    u16*   Wqkvt = (u16*)(ws + 8 * MB);      // 6 MiB
    u16*   Wot   = (u16*)(ws + 14 * MB);     // 2 MiB
    u16*   W1t   = (u16*)(ws + 16 * MB);     // 8 MiB
    u16*   W2t   = (u16*)(ws + 24 * MB);     // 8 MiB (live through FFN2)
    u16*   Qab   = (u16*)(ws + 32 * MB);     // 8 MiB each [32,72)
    u16*   Qcb   = (u16*)(ws + 40 * MB);
    u16*   Kab   = (u16*)(ws + 48 * MB);
    u16*   Kcb   = (u16*)(ws + 56 * MB);
    u16*   Vtb   = (u16*)(ws + 64 * MB);
    u16*   Eab   = (u16*)(ws + 72 * MB);     // 128 MiB [72,200)
    u16*   Ecb   = (u16*)(ws + 200 * MB);    // 128 MiB [200,328)
    float* denA2 = (float*)(ws + 328 * MB);  // 512 KiB ([2][65536])
    float* denC2 = (float*)(ws + 329 * MB);  // 512 KiB
    float* ctxP  = (float*)(ws + 330 * MB);  // 32 MiB [330,362) ([2][4M])
    u16*   ctx   = (u16*)(ws + 362 * MB);    // 8 MiB (dead after Wo gemm)
    float* ctxWo = (float*)(ws + 32 * MB);   // reuse Qab/Qcb (dead after attn)
    float* out1  = (float*)(ws + 48 * MB);   // reuse Kab/Kcb (live to LN2)
    u16*   out1b = (u16*)(ws + 64 * MB);     // reuse Vtb
    u16*   rb    = (u16*)(ws + 72 * MB);     // 32 MiB reuse Eab (dead after k_pv2)
    float* ff2   = (float*)(ws + 0 * MB);    // 16 MiB reuse xb+weights (dead)

    dim3 tb(32, 8);
    // 1. casts / weight prep
    k_f2b<<<4096, 256, 0, stream>>>(x, xb, 1048576);
    k_wtrans<<<dim3(32, 32), tb, 0, stream>>>(Wq, Wqkvt, 1024, 1024);
    k_wtrans<<<dim3(32, 32), tb, 0, stream>>>(Wk, Wqkvt + 1024 * 1024, 1024, 1024);
    k_wtrans<<<dim3(32, 32), tb, 0, stream>>>(Wv, Wqkvt + 2 * 1024 * 1024, 1024, 1024);
    k_wtrans<<<dim3(32, 32), tb, 0, stream>>>(Wo, Wot, 1024, 1024);
    k_wtrans<<<dim3(128, 32), tb, 0, stream>>>(W1, W1t, 1024, 4096);
    k_wtrans<<<dim3(32, 128), tb, 0, stream>>>(W2, W2t, 4096, 1024);
    // 2. fused QKV projection + epilogues (Qa/Qc/Ka/Kc flat, Vt transposed)
    gemm_qkv<<<dim3(24, 32), 256, 0, stream>>>(xb, Wqkvt, bq, bk, bv, rel,
                                               Qab, Qcb, Kab, Kcb, Vtb);
    // 3. attention: merged two-stage, k-split x2 (grid 2048 -> ~2x occupancy)
    k_qke2<<<2048, 256, 0, stream>>>(Qab, Qcb, Kab, Kcb, Eab, Ecb, denA2, denC2);
    k_pv2<<<2048, 256, 0, stream>>>(Eab, Ecb, Vtb, adjm, comm, denA2, denC2, ctxP);
    k_comb2<<<4096, 256, 0, stream>>>(ctxP, ctx, 1048576);
    // 4. output projection + LN1
    gemm_bt64<<<dim3(16, 32), 256, 0, stream>>>(ctx, Wot, ctxWo, 4096, 1024, 1024);
    k_ln<<<4096, 256, 0, stream>>>(ctxWo, bo, x, g1, be1, out1, out1b);
    // 5. FFN
    gemm_bt<1><<<dim3(32, 32), 256, 0, stream>>>(out1b, W1t, rb, 4096, 4096, 1024, b1);
    gemm_bt64<<<dim3(16, 32), 256, 0, stream>>>(rb, W2t, ff2, 4096, 1024, 4096);
    // 6. LN2 -> final output
    k_ln<<<4096, 256, 0, stream>>>(ff2, b2, out1, g2, be2, out, nullptr);
}

// Round 11
// 618.340 us; speedup vs baseline: 1.0853x; 1.0458x over previous
//
#include <hip/hip_runtime.h>
#include <hip/hip_bf16.h>

typedef __attribute__((ext_vector_type(8))) short s16x8;
typedef __attribute__((ext_vector_type(4))) float f32x4;
typedef unsigned short u16;
typedef unsigned int u32;

__device__ __forceinline__ u16 f2b(float f) {
    u32 u = __float_as_uint(f);
    u32 r = (u + 0x7fffu + ((u >> 16) & 1u)) >> 16;  // RNE bf16
    return (u16)r;
}

#define MFMA16(a, b, c) __builtin_amdgcn_mfma_f32_16x16x32_bf16(a, b, c, 0, 0, 0)
#define GLDS(gp, lp)                                                              \
    __builtin_amdgcn_global_load_lds((const __attribute__((address_space(1))) void*)(gp), \
                                     (__attribute__((address_space(3))) void*)(lp), 16, 0, 0)

// --- inline-asm 16B loads: issued at the asm point, complete at s_waitcnt. ---
// Forces RA to give every in-flight load a distinct dest quad (parallel MLP).
__device__ __forceinline__ void gl_h8(s16x8* d, const u16* p) {
    asm volatile("global_load_dwordx4 %0, %1, off" : "=v"(*d) : "v"(p));
}
__device__ __forceinline__ void gl_f4(float4* d, const float* p) {
    asm volatile("global_load_dwordx4 %0, %1, off" : "=v"(*d) : "v"(p));
}
#define VWAIT0()                                      \
    asm volatile("s_waitcnt vmcnt(0)" ::: "memory"); \
    __builtin_amdgcn_sched_barrier(0)

// ---------------- elementwise: f32 -> bf16 ----------------
__global__ void k_f2b(const float* __restrict__ in, u16* __restrict__ out, int n4) {
    int i = blockIdx.x * 256 + threadIdx.x;
    if (i >= n4) return;
    float4 v = ((const float4*)in)[i];
    ushort4 o;
    o.x = f2b(v.x); o.y = f2b(v.y); o.z = f2b(v.z); o.w = f2b(v.w);
    ((ushort4*)out)[i] = o;
}

// ---------------- weight transpose+convert: W[K,N] f32 -> Wt[N,K] bf16 ----------------
__global__ void k_wtrans(const float* __restrict__ W, u16* __restrict__ Wt, int K, int N) {
    __shared__ float t[32][33];
    int bx = blockIdx.x * 32, by = blockIdx.y * 32;
    int tx = threadIdx.x, ty = threadIdx.y;
    for (int i = 0; i < 32; i += 8)
        t[ty + i][tx] = W[(size_t)(by + ty + i) * N + bx + tx];
    __syncthreads();
    for (int i = 0; i < 32; i += 8)
        Wt[(size_t)(bx + ty + i) * K + by + tx] = f2b(t[tx][ty + i]);
}

// ---------------- fused QKV GEMM: [4096,1024]@[3072,1024]^T, epilogue writes Qa/Qc/Ka/Kc/Vt bf16 ----------------
__global__ __launch_bounds__(256) void gemm_qkv(const u16* __restrict__ A, const u16* __restrict__ Bt,
                                                const float* __restrict__ bq, const float* __restrict__ bk,
                                                const float* __restrict__ bv, const float* __restrict__ rel,
                                                u16* __restrict__ Qa, u16* __restrict__ Qc,
                                                u16* __restrict__ Ka, u16* __restrict__ Kc,
                                                u16* __restrict__ Vt) {
    __shared__ __align__(16) short lA[128 * 64];
    __shared__ __align__(16) short lB[128 * 64];
    const int tid = threadIdx.x, lane = tid & 63, w = tid >> 6;
    const int l15 = lane & 15, lg = lane >> 4;
    const int wr = w >> 1, wc = w & 1;
    const int m0 = blockIdx.y * 128, n0 = blockIdx.x * 128;
    const int KK = 1024;
    f32x4 acc[4][4] = {};

    for (int k0 = 0; k0 < KK; k0 += 64) {
        #pragma unroll
        for (int i = 0; i < 4; i++) {
            int chunk = w * 4 + i;
            int arow = m0 + chunk * 8 + (lane >> 3);
            GLDS(A + (size_t)arow * KK + k0 + (lane & 7) * 8, (short*)lA + chunk * 512);
            int brow = n0 + chunk * 8 + (lane >> 3);
            GLDS(Bt + (size_t)brow * KK + k0 + (lane & 7) * 8, (short*)lB + chunk * 512);
        }
        __syncthreads();
        #pragma unroll
        for (int ks = 0; ks < 2; ks++) {
            s16x8 af[4], bfr[4];
            #pragma unroll
            for (int m = 0; m < 4; m++)
                af[m] = *(const s16x8*)&lA[(wr * 64 + m * 16 + l15) * 64 + ks * 32 + lg * 8];
            #pragma unroll
            for (int n = 0; n < 4; n++)
                bfr[n] = *(const s16x8*)&lB[(wc * 64 + n * 16 + l15) * 64 + ks * 32 + lg * 8];
            #pragma unroll
            for (int m = 0; m < 4; m++)
                #pragma unroll
                for (int n = 0; n < 4; n++)
                    acc[m][n] = MFMA16(af[m], bfr[n], acc[m][n]);
        }
        __syncthreads();
    }
    const int rbase = m0 + wr * 64, cbase = n0 + wc * 64;
    const int seg = cbase >> 10;  // uniform per block (128-wide tiles)
    #pragma unroll
    for (int m = 0; m < 4; m++)
        #pragma unroll
        for (int n = 0; n < 4; n++) {
            int col = cbase + n * 16 + l15;
            int c1 = col & 1023, d = col & 63;
            int row0 = rbase + m * 16 + lg * 4;
            if (seg == 0) {
                float bb = bq[c1], r0 = rel[d], r1 = rel[64 + d];
                #pragma unroll
                for (int r = 0; r < 4; r++) {
                    float v = acc[m][n][r] + bb;
                    size_t o = (size_t)(row0 + r) * 1024 + c1;
                    Qa[o] = f2b(v + r0);
                    Qc[o] = f2b(v + r1);
                }
            } else if (seg == 1) {
                float bb = bk[c1], r0 = rel[d], r1 = rel[64 + d];
                #pragma unroll
                for (int r = 0; r < 4; r++) {
                    float v = acc[m][n][r] + bb;
                    size_t o = (size_t)(row0 + r) * 1024 + c1;
                    Ka[o] = f2b(v + r0);
                    Kc[o] = f2b(v + r1);
                }
            } else {
                float bb = bv[c1];
                #pragma unroll
                for (int r = 0; r < 4; r++) {
                    int row = row0 + r;
                    size_t o = (size_t)(row >> 6) * 65536 + (size_t)d * 1024 + (row & 63) * 16 + (c1 >> 6);
                    Vt[o] = f2b(acc[m][n][r] + bb);
                }
            }
        }
}

// ---------------- GEMM 128x128, EPI 1: bf16(relu(acc+bias)) ----------------
template <int EPI>
__global__ __launch_bounds__(256) void gemm_bt(const u16* __restrict__ A, const u16* __restrict__ Bt,
                                               void* __restrict__ Cv, int M, int N, int K,
                                               const float* __restrict__ bias) {
    __shared__ __align__(16) short lA[128 * 64];
    __shared__ __align__(16) short lB[128 * 64];
    const int tid = threadIdx.x, lane = tid & 63, w = tid >> 6;
    const int l15 = lane & 15, lg = lane >> 4;
    const int wr = w >> 1, wc = w & 1;
    const int m0 = blockIdx.y * 128, n0 = blockIdx.x * 128;
    f32x4 acc[4][4] = {};

    for (int k0 = 0; k0 < K; k0 += 64) {
        #pragma unroll
        for (int i = 0; i < 4; i++) {
            int chunk = w * 4 + i;
            int arow = m0 + chunk * 8 + (lane >> 3);
            GLDS(A + (size_t)arow * K + k0 + (lane & 7) * 8, (short*)lA + chunk * 512);
            int brow = n0 + chunk * 8 + (lane >> 3);
            GLDS(Bt + (size_t)brow * K + k0 + (lane & 7) * 8, (short*)lB + chunk * 512);
        }
        __syncthreads();
        #pragma unroll
        for (int ks = 0; ks < 2; ks++) {
            s16x8 af[4], bfr[4];
            #pragma unroll
            for (int m = 0; m < 4; m++)
                af[m] = *(const s16x8*)&lA[(wr * 64 + m * 16 + l15) * 64 + ks * 32 + lg * 8];
            #pragma unroll
            for (int n = 0; n < 4; n++)
                bfr[n] = *(const s16x8*)&lB[(wc * 64 + n * 16 + l15) * 64 + ks * 32 + lg * 8];
            #pragma unroll
            for (int m = 0; m < 4; m++)
                #pragma unroll
                for (int n = 0; n < 4; n++)
                    acc[m][n] = MFMA16(af[m], bfr[n], acc[m][n]);
        }
        __syncthreads();
    }
    const int rbase = m0 + wr * 64, cbase = n0 + wc * 64;
    #pragma unroll
    for (int m = 0; m < 4; m++)
        #pragma unroll
        for (int n = 0; n < 4; n++) {
            int col = cbase + n * 16 + l15;
            int row0 = rbase + m * 16 + lg * 4;
            u16* C = (u16*)Cv;
            float bv = bias[col];
            #pragma unroll
            for (int r = 0; r < 4; r++)
                C[(size_t)(row0 + r) * N + col] = f2b(fmaxf(acc[m][n][r] + bv, 0.f));
        }
}

// ---------------- GEMM 128x64 f32-out ----------------
__global__ __launch_bounds__(256) void gemm_bt64(const u16* __restrict__ A, const u16* __restrict__ Bt,
                                                 float* __restrict__ C, int M, int N, int K) {
    __shared__ __align__(16) short lA[128 * 64];
    __shared__ __align__(16) short lB[64 * 64];
    const int tid = threadIdx.x, lane = tid & 63, w = tid >> 6;
    const int l15 = lane & 15, lg = lane >> 4;
    const int m0 = blockIdx.y * 128, n0 = blockIdx.x * 64;
    f32x4 acc[2][4] = {};

    for (int k0 = 0; k0 < K; k0 += 64) {
        #pragma unroll
        for (int i = 0; i < 4; i++) {
            int chunk = w * 4 + i;
            int arow = m0 + chunk * 8 + (lane >> 3);
            GLDS(A + (size_t)arow * K + k0 + (lane & 7) * 8, (short*)lA + chunk * 512);
        }
        #pragma unroll
        for (int i = 0; i < 2; i++) {
            int chunk = w * 2 + i;
            int brow = n0 + chunk * 8 + (lane >> 3);
            GLDS(Bt + (size_t)brow * K + k0 + (lane & 7) * 8, (short*)lB + chunk * 512);
        }
        __syncthreads();
        #pragma unroll
        for (int ks = 0; ks < 2; ks++) {
            s16x8 af[2], bfr[4];
            #pragma unroll
            for (int m = 0; m < 2; m++)
                af[m] = *(const s16x8*)&lA[(w * 32 + m * 16 + l15) * 64 + ks * 32 + lg * 8];
            #pragma unroll
            for (int n = 0; n < 4; n++)
                bfr[n] = *(const s16x8*)&lB[(n * 16 + l15) * 64 + ks * 32 + lg * 8];
            #pragma unroll
            for (int m = 0; m < 2; m++)
                #pragma unroll
                for (int n = 0; n < 4; n++)
                    acc[m][n] = MFMA16(af[m], bfr[n], acc[m][n]);
        }
        __syncthreads();
    }
    #pragma unroll
    for (int m = 0; m < 2; m++)
        #pragma unroll
        for (int n = 0; n < 4; n++) {
            int col = n0 + n * 16 + l15;
            int row0 = m0 + w * 32 + m * 16 + lg * 4;
            #pragma unroll
            for (int r = 0; r < 4; r++)
                C[(size_t)(row0 + r) * N + col] = acc[m][n][r];
        }
}

// ---------------- fused single-pass attention, map on blockIdx.z, ASM parallel loads ----------------
// All 20 loads/iter issued back-to-back as volatile asm (RA must keep 20 dest quads live
// -> genuine MLP), one vmcnt(0)+sched_barrier before compute. No E round-trip.
__global__ __launch_bounds__(256) void k_attnf(const u16* __restrict__ Qa, const u16* __restrict__ Qc,
                                               const u16* __restrict__ Ka, const u16* __restrict__ Kc,
                                               const u16* __restrict__ Vt,
                                               const float* __restrict__ adjm, const float* __restrict__ comm,
                                               float* __restrict__ ctxA, float* __restrict__ ctxC) {
    const int bid = blockIdx.x;
    const int xcd = bid & 7, j = bid >> 3;
    const int g = xcd * 8 + (j & 7), qt = j >> 3;
    const int s = blockIdx.z;
    const u16* __restrict__ Q = s ? Qc : Qa;
    const u16* __restrict__ K = s ? Kc : Ka;
    const float* __restrict__ mask = s ? comm : adjm;
    float* __restrict__ ctxp = s ? ctxC : ctxA;

    const int tid = threadIdx.x, lane = tid & 63, w = tid >> 6;
    const int l15 = lane & 15, lg = lane >> 4;
    __shared__ __align__(16) float lE[4][16][68];

    const int q0 = qt * 64 + w * 16;
    const size_t gQ = (size_t)g * 65536;
    const float* __restrict__ mrow = mask + (size_t)g * 1048576 + (size_t)(q0 + l15) * 1024 + lg * 8;
    const float scale = 0.125f;

    s16x8 qf[2];
    #pragma unroll
    for (int ks = 0; ks < 2; ks++)
        qf[ks] = *(const s16x8*)(Q + gQ + (size_t)(q0 + l15) * 64 + ks * 32 + lg * 8);

    f32x4 ca[4] = {};
    float la[4] = {0.f, 0.f, 0.f, 0.f};

    #pragma unroll 1
    for (int it = 0; it < 16; it++) {
        const int kb = it * 64;
        float4 mf[4];
        s16x8 kf[8], vf[8];
        // --- issue ALL loads back-to-back (volatile asm preserves order; no waits between) ---
        gl_f4(&mf[0], mrow + kb);
        gl_f4(&mf[1], mrow + kb + 4);
        gl_f4(&mf[2], mrow + kb + 32);
        gl_f4(&mf[3], mrow + kb + 36);
        #pragma unroll
        for (int ks = 0; ks < 2; ks++)
            #pragma unroll
            for (int n = 0; n < 4; n++)
                gl_h8(&kf[ks * 4 + n], K + gQ + (size_t)(kb + n * 16 + l15) * 64 + ks * 32 + lg * 8);
        #pragma unroll
        for (int ks = 0; ks < 2; ks++)
            #pragma unroll
            for (int d = 0; d < 4; d++)
                gl_h8(&vf[ks * 4 + d], Vt + gQ + (size_t)(d * 16 + l15) * 1024 + kb + ks * 32 + lg * 8);
        VWAIT0();  // one wait for all 20; latencies overlap
        // --- QK^T ---
        f32x4 sa[4] = {};
        #pragma unroll
        for (int ks = 0; ks < 2; ks++)
            #pragma unroll
            for (int n = 0; n < 4; n++)
                sa[n] = MFMA16(qf[ks], kf[ks * 4 + n], sa[n]);
        // --- exp (C-layout) -> LDS -> A-layout ---
        #pragma unroll
        for (int n = 0; n < 4; n++)
            #pragma unroll
            for (int r = 0; r < 4; r++) {
                float e = __expf(sa[n][r] * scale);
                la[r] += e;
                lE[w][lg * 4 + r][n * 16 + l15] = e;
            }
        // --- mask-mul + pack + PV ---
        #pragma unroll
        for (int ks = 0; ks < 2; ks++) {
            const float* ep = &lE[w][l15][ks * 32 + lg * 8];
            float4 e0 = *(const float4*)ep, e1 = *(const float4*)(ep + 4);
            union { s16x8 v; u16 u[8]; } pf;
            pf.u[0] = f2b(e0.x * mf[ks * 2].x); pf.u[1] = f2b(e0.y * mf[ks * 2].y);
            pf.u[2] = f2b(e0.z * mf[ks * 2].z); pf.u[3] = f2b(e0.w * mf[ks * 2].w);
            pf.u[4] = f2b(e1.x * mf[ks * 2 + 1].x); pf.u[5] = f2b(e1.y * mf[ks * 2 + 1].y);
            pf.u[6] = f2b(e1.z * mf[ks * 2 + 1].z); pf.u[7] = f2b(e1.w * mf[ks * 2 + 1].w);
            #pragma unroll
            for (int d = 0; d < 4; d++)
                ca[d] = MFMA16(pf.v, vf[ks * 4 + d], ca[d]);
        }
    }
    // deferred denominator reduction over the 16-lane groups
    #pragma unroll
    for (int r = 0; r < 4; r++)
        #pragma unroll
        for (int m = 8; m >= 1; m >>= 1)
            la[r] += __shfl_xor(la[r], m);
    #pragma unroll
    for (int r = 0; r < 4; r++) {
        float il = 1.f / la[r];
        int row = q0 + lg * 4 + r;
        #pragma unroll
        for (int d = 0; d < 4; d++)
            ctxp[gQ + (size_t)row * 64 + d * 16 + l15] = ca[d][r] * il;
    }
}

// ---------------- combine the two maps' normalized partial contexts -> bf16 ----------------
__global__ void k_comb(const float* __restrict__ A, const float* __restrict__ C,
                       u16* __restrict__ out, int n4) {
    int i = blockIdx.x * 256 + threadIdx.x;
    if (i >= n4) return;
    float4 a = ((const float4*)A)[i];
    float4 c = ((const float4*)C)[i];
    ushort4 o;
    o.x = f2b(a.x + c.x); o.y = f2b(a.y + c.y);
    o.z = f2b(a.z + c.z); o.w = f2b(a.w + c.w);
    ((ushort4*)out)[i] = o;
}

// ---------------- row LayerNorm ----------------
__global__ __launch_bounds__(256) void k_ln(const float* __restrict__ a, const float* __restrict__ bias,
                                            const float* __restrict__ resid, const float* __restrict__ gamma,
                                            const float* __restrict__ beta, float* __restrict__ out,
                                            u16* __restrict__ outb) {
    const int row = blockIdx.x, tid = threadIdx.x;
    const size_t base = (size_t)row * 1024 + tid * 4;
    float4 av = *(const float4*)(a + base);
    float4 rv = *(const float4*)(resid + base);
    float4 bv = *(const float4*)(bias + tid * 4);
    float t0 = av.x + rv.x + bv.x, t1 = av.y + rv.y + bv.y;
    float t2 = av.z + rv.z + bv.z, t3 = av.w + rv.w + bv.w;
    __shared__ float red[4];
    float s = t0 + t1 + t2 + t3;
    #pragma unroll
    for (int m = 32; m >= 1; m >>= 1) s += __shfl_xor(s, m);
    int w = tid >> 6;
    if ((tid & 63) == 0) red[w] = s;
    __syncthreads();
    float mean = (red[0] + red[1] + red[2] + red[3]) * (1.f / 1024.f);
    float d0 = t0 - mean, d1 = t1 - mean, d2 = t2 - mean, d3 = t3 - mean;
    float q = d0 * d0 + d1 * d1 + d2 * d2 + d3 * d3;
    __syncthreads();
    #pragma unroll
    for (int m = 32; m >= 1; m >>= 1) q += __shfl_xor(q, m);
    if ((tid & 63) == 0) red[w] = q;
    __syncthreads();
    float var = (red[0] + red[1] + red[2] + red[3]) * (1.f / 1024.f);
    float rs = rsqrtf(var + 1e-5f);
    float4 gv = *(const float4*)(gamma + tid * 4);
    float4 bev = *(const float4*)(beta + tid * 4);
    float o0 = d0 * rs * gv.x + bev.x, o1 = d1 * rs * gv.y + bev.y;
    float o2 = d0 == d0 ? d2 * rs * gv.z + bev.z : 0.f, o3 = d3 * rs * gv.w + bev.w;
    o2 = d2 * rs * gv.z + bev.z;
    *(float4*)(out + base) = make_float4(o0, o1, o2, o3);
    if (outb) {
        ushort4 ob;
        ob.x = f2b(o0); ob.y = f2b(o1); ob.z = f2b(o2); ob.w = f2b(o3);
        *(ushort4*)(outb + base) = ob;
    }
}

extern "C" void kernel_launch(void* const* d_in, const int* in_sizes, int n_in,
                              void* d_out, int out_size, void* d_ws, size_t ws_size,
                              hipStream_t stream) {
    const float* x    = (const float*)d_in[0];
    const float* adjm = (const float*)d_in[1];
    const float* comm = (const float*)d_in[2];
    const float* rel  = (const float*)d_in[3];
    const float* Wq   = (const float*)d_in[4];
    const float* bq   = (const float*)d_in[5];
    const float* Wk   = (const float*)d_in[6];
    const float* bk   = (const float*)d_in[7];
    const float* Wv   = (const float*)d_in[8];
    const float* bv   = (const float*)d_in[9];
    const float* Wo   = (const float*)d_in[10];
    const float* bo   = (const float*)d_in[11];
    const float* g1   = (const float*)d_in[12];
    const float* be1  = (const float*)d_in[13];
    const float* W1   = (const float*)d_in[14];
    const float* b1   = (const float*)d_in[15];
    const float* W2   = (const float*)d_in[16];
    const float* b2   = (const float*)d_in[17];
    const float* g2   = (const float*)d_in[18];
    const float* be2  = (const float*)d_in[19];
    float* out = (float*)d_out;

    char* ws = (char*)d_ws;
    const size_t MB = 1048576;
    u16*   xb    = (u16*)(ws + 0 * MB);      // 8 MiB (dead after gemm_qkv)
    u16*   Wqkvt = (u16*)(ws + 8 * MB);      // 6 MiB
    u16*   Wot   = (u16*)(ws + 14 * MB);     // 2 MiB
    u16*   W1t   = (u16*)(ws + 16 * MB);     // 8 MiB
    u16*   W2t   = (u16*)(ws + 24 * MB);     // 8 MiB (live through FFN2)
    u16*   Qab   = (u16*)(ws + 32 * MB);     // 8 MiB each [32,72)
    u16*   Qcb   = (u16*)(ws + 40 * MB);
    u16*   Kab   = (u16*)(ws + 48 * MB);
    u16*   Kcb   = (u16*)(ws + 56 * MB);
    u16*   Vtb   = (u16*)(ws + 64 * MB);
    float* ctxA  = (float*)(ws + 72 * MB);   // 16 MiB
    float* ctxC  = (float*)(ws + 88 * MB);   // 16 MiB
    u16*   ctx   = (u16*)(ws + 104 * MB);    // 8 MiB (dead after Wo gemm)
    float* ctxWo = (float*)(ws + 32 * MB);   // reuse Qab/Qcb (dead after attn)
    float* out1  = (float*)(ws + 48 * MB);   // reuse Kab/Kcb (live to LN2)
    u16*   out1b = (u16*)(ws + 64 * MB);     // reuse Vtb
    u16*   rb    = (u16*)(ws + 72 * MB);     // 32 MiB reuse ctxA/ctxC (dead after comb)
    float* ff2   = (float*)(ws + 0 * MB);    // 16 MiB reuse xb+weights (dead)

    dim3 tb(32, 8);
    // 1. casts / weight prep
    k_f2b<<<4096, 256, 0, stream>>>(x, xb, 1048576);
    k_wtrans<<<dim3(32, 32), tb, 0, stream>>>(Wq, Wqkvt, 1024, 1024);
    k_wtrans<<<dim3(32, 32), tb, 0, stream>>>(Wk, Wqkvt + 1024 * 1024, 1024, 1024);
    k_wtrans<<<dim3(32, 32), tb, 0, stream>>>(Wv, Wqkvt + 2 * 1024 * 1024, 1024, 1024);
    k_wtrans<<<dim3(32, 32), tb, 0, stream>>>(Wo, Wot, 1024, 1024);
    k_wtrans<<<dim3(128, 32), tb, 0, stream>>>(W1, W1t, 1024, 4096);
    k_wtrans<<<dim3(32, 128), tb, 0, stream>>>(W2, W2t, 4096, 1024);
    // 2. fused QKV projection + epilogues (Qa/Qc/Ka/Kc flat, Vt transposed)
    gemm_qkv<<<dim3(24, 32), 256, 0, stream>>>(xb, Wqkvt, bq, bk, bv, rel,
                                               Qab, Qcb, Kab, Kcb, Vtb);
    // 3. fused one-pass dual-mask attention (asm parallel loads) + combine
    k_attnf<<<dim3(1024, 1, 2), 256, 0, stream>>>(Qab, Qcb, Kab, Kcb, Vtb, adjm, comm, ctxA, ctxC);
    k_comb<<<4096, 256, 0, stream>>>(ctxA, ctxC, ctx, 1048576);
    // 4. output projection + LN1
    gemm_bt64<<<dim3(16, 32), 256, 0, stream>>>(ctx, Wot, ctxWo, 4096, 1024, 1024);
    k_ln<<<4096, 256, 0, stream>>>(ctxWo, bo, x, g1, be1, out1, out1b);
    // 5. FFN
    gemm_bt<1><<<dim3(32, 32), 256, 0, stream>>>(out1b, W1t, rb, 4096, 4096, 1024, b1);
    gemm_bt64<<<dim3(16, 32), 256, 0, stream>>>(rb, W2t, ff2, 4096, 1024, 4096);
    // 6. LN2 -> final output
    k_ln<<<4096, 256, 0, stream>>>(ff2, b2, out1, g2, be2, out, nullptr);
}

// Round 12
// 562.513 us; speedup vs baseline: 1.1930x; 1.0992x over previous
//
#include <hip/hip_runtime.h>
#include <hip/hip_bf16.h>

typedef __attribute__((ext_vector_type(8))) short s16x8;
typedef __attribute__((ext_vector_type(4))) float f32x4;
typedef unsigned short u16;
typedef unsigned int u32;

__device__ __forceinline__ u16 f2b(float f) {
    u32 u = __float_as_uint(f);
    u32 r = (u + 0x7fffu + ((u >> 16) & 1u)) >> 16;  // RNE bf16
    return (u16)r;
}
__device__ __forceinline__ float b2f(u16 b) {
    return __uint_as_float(((u32)b) << 16);
}

#define MFMA16(a, b, c) __builtin_amdgcn_mfma_f32_16x16x32_bf16(a, b, c, 0, 0, 0)
#define GLDS(gp, lp)                                                              \
    __builtin_amdgcn_global_load_lds((const __attribute__((address_space(1))) void*)(gp), \
                                     (__attribute__((address_space(3))) void*)(lp), 16, 0, 0)

// ---------------- elementwise: f32 -> bf16 ----------------
__global__ void k_f2b(const float* __restrict__ in, u16* __restrict__ out, int n4) {
    int i = blockIdx.x * 256 + threadIdx.x;
    if (i >= n4) return;
    float4 v = ((const float4*)in)[i];
    ushort4 o;
    o.x = f2b(v.x); o.y = f2b(v.y); o.z = f2b(v.z); o.w = f2b(v.w);
    ((ushort4*)out)[i] = o;
}

// ---------------- weight transpose+convert: W[K,N] f32 -> Wt[N,K] bf16 ----------------
__global__ void k_wtrans(const float* __restrict__ W, u16* __restrict__ Wt, int K, int N) {
    __shared__ float t[32][33];
    int bx = blockIdx.x * 32, by = blockIdx.y * 32;
    int tx = threadIdx.x, ty = threadIdx.y;
    for (int i = 0; i < 32; i += 8)
        t[ty + i][tx] = W[(size_t)(by + ty + i) * N + bx + tx];
    __syncthreads();
    for (int i = 0; i < 32; i += 8)
        Wt[(size_t)(bx + ty + i) * K + by + tx] = f2b(t[tx][ty + i]);
}

// ---------------- fused QKV GEMM: epilogue writes Qb/Kb (bias only) + transposed Vt ----------------
__global__ __launch_bounds__(256) void gemm_qkv(const u16* __restrict__ A, const u16* __restrict__ Bt,
                                                const float* __restrict__ bq, const float* __restrict__ bk,
                                                const float* __restrict__ bv,
                                                u16* __restrict__ Qb, u16* __restrict__ Kb,
                                                u16* __restrict__ Vt) {
    __shared__ __align__(16) short lA[128 * 64];
    __shared__ __align__(16) short lB[128 * 64];
    const int tid = threadIdx.x, lane = tid & 63, w = tid >> 6;
    const int l15 = lane & 15, lg = lane >> 4;
    const int wr = w >> 1, wc = w & 1;
    const int m0 = blockIdx.y * 128, n0 = blockIdx.x * 128;
    const int KK = 1024;
    f32x4 acc[4][4] = {};

    for (int k0 = 0; k0 < KK; k0 += 64) {
        #pragma unroll
        for (int i = 0; i < 4; i++) {
            int chunk = w * 4 + i;
            int arow = m0 + chunk * 8 + (lane >> 3);
            GLDS(A + (size_t)arow * KK + k0 + (lane & 7) * 8, (short*)lA + chunk * 512);
            int brow = n0 + chunk * 8 + (lane >> 3);
            GLDS(Bt + (size_t)brow * KK + k0 + (lane & 7) * 8, (short*)lB + chunk * 512);
        }
        __syncthreads();
        #pragma unroll
        for (int ks = 0; ks < 2; ks++) {
            s16x8 af[4], bfr[4];
            #pragma unroll
            for (int m = 0; m < 4; m++)
                af[m] = *(const s16x8*)&lA[(wr * 64 + m * 16 + l15) * 64 + ks * 32 + lg * 8];
            #pragma unroll
            for (int n = 0; n < 4; n++)
                bfr[n] = *(const s16x8*)&lB[(wc * 64 + n * 16 + l15) * 64 + ks * 32 + lg * 8];
            #pragma unroll
            for (int m = 0; m < 4; m++)
                #pragma unroll
                for (int n = 0; n < 4; n++)
                    acc[m][n] = MFMA16(af[m], bfr[n], acc[m][n]);
        }
        __syncthreads();
    }
    const int rbase = m0 + wr * 64, cbase = n0 + wc * 64;
    const int seg = cbase >> 10;
    #pragma unroll
    for (int m = 0; m < 4; m++)
        #pragma unroll
        for (int n = 0; n < 4; n++) {
            int col = cbase + n * 16 + l15;
            int c1 = col & 1023, d = col & 63;
            int row0 = rbase + m * 16 + lg * 4;
            if (seg == 0) {
                float bb = bq[c1];
                #pragma unroll
                for (int r = 0; r < 4; r++)
                    Qb[(size_t)(row0 + r) * 1024 + c1] = f2b(acc[m][n][r] + bb);
            } else if (seg == 1) {
                float bb = bk[c1];
                #pragma unroll
                for (int r = 0; r < 4; r++)
                    Kb[(size_t)(row0 + r) * 1024 + c1] = f2b(acc[m][n][r] + bb);
            } else {
                float bb = bv[c1];
                #pragma unroll
                for (int r = 0; r < 4; r++) {
                    int row = row0 + r;
                    size_t o = (size_t)(row >> 6) * 65536 + (size_t)d * 1024 + (row & 63) * 16 + (c1 >> 6);
                    Vt[o] = f2b(acc[m][n][r] + bb);
                }
            }
        }
}

// ---------------- GEMM 128x128, EPI 1: bf16(relu(acc+bias)) ----------------
template <int EPI>
__global__ __launch_bounds__(256) void gemm_bt(const u16* __restrict__ A, const u16* __restrict__ Bt,
                                               void* __restrict__ Cv, int M, int N, int K,
                                               const float* __restrict__ bias) {
    __shared__ __align__(16) short lA[128 * 64];
    __shared__ __align__(16) short lB[128 * 64];
    const int tid = threadIdx.x, lane = tid & 63, w = tid >> 6;
    const int l15 = lane & 15, lg = lane >> 4;
    const int wr = w >> 1, wc = w & 1;
    const int m0 = blockIdx.y * 128, n0 = blockIdx.x * 128;
    f32x4 acc[4][4] = {};

    for (int k0 = 0; k0 < K; k0 += 64) {
        #pragma unroll
        for (int i = 0; i < 4; i++) {
            int chunk = w * 4 + i;
            int arow = m0 + chunk * 8 + (lane >> 3);
            GLDS(A + (size_t)arow * K + k0 + (lane & 7) * 8, (short*)lA + chunk * 512);
            int brow = n0 + chunk * 8 + (lane >> 3);
            GLDS(Bt + (size_t)brow * K + k0 + (lane & 7) * 8, (short*)lB + chunk * 512);
        }
        __syncthreads();
        #pragma unroll
        for (int ks = 0; ks < 2; ks++) {
            s16x8 af[4], bfr[4];
            #pragma unroll
            for (int m = 0; m < 4; m++)
                af[m] = *(const s16x8*)&lA[(wr * 64 + m * 16 + l15) * 64 + ks * 32 + lg * 8];
            #pragma unroll
            for (int n = 0; n < 4; n++)
                bfr[n] = *(const s16x8*)&lB[(wc * 64 + n * 16 + l15) * 64 + ks * 32 + lg * 8];
            #pragma unroll
            for (int m = 0; m < 4; m++)
                #pragma unroll
                for (int n = 0; n < 4; n++)
                    acc[m][n] = MFMA16(af[m], bfr[n], acc[m][n]);
        }
        __syncthreads();
    }
    const int rbase = m0 + wr * 64, cbase = n0 + wc * 64;
    #pragma unroll
    for (int m = 0; m < 4; m++)
        #pragma unroll
        for (int n = 0; n < 4; n++) {
            int col = cbase + n * 16 + l15;
            int row0 = rbase + m * 16 + lg * 4;
            u16* C = (u16*)Cv;
            float bv = bias[col];
            #pragma unroll
            for (int r = 0; r < 4; r++)
                C[(size_t)(row0 + r) * N + col] = f2b(fmaxf(acc[m][n][r] + bv, 0.f));
        }
}

// ---------------- GEMM 128x64 f32-out ----------------
__global__ __launch_bounds__(256) void gemm_bt64(const u16* __restrict__ A, const u16* __restrict__ Bt,
                                                 float* __restrict__ C, int M, int N, int K) {
    __shared__ __align__(16) short lA[128 * 64];
    __shared__ __align__(16) short lB[64 * 64];
    const int tid = threadIdx.x, lane = tid & 63, w = tid >> 6;
    const int l15 = lane & 15, lg = lane >> 4;
    const int m0 = blockIdx.y * 128, n0 = blockIdx.x * 64;
    f32x4 acc[2][4] = {};

    for (int k0 = 0; k0 < K; k0 += 64) {
        #pragma unroll
        for (int i = 0; i < 4; i++) {
            int chunk = w * 4 + i;
            int arow = m0 + chunk * 8 + (lane >> 3);
            GLDS(A + (size_t)arow * K + k0 + (lane & 7) * 8, (short*)lA + chunk * 512);
        }
        #pragma unroll
        for (int i = 0; i < 2; i++) {
            int chunk = w * 2 + i;
            int brow = n0 + chunk * 8 + (lane >> 3);
            GLDS(Bt + (size_t)brow * K + k0 + (lane & 7) * 8, (short*)lB + chunk * 512);
        }
        __syncthreads();
        #pragma unroll
        for (int ks = 0; ks < 2; ks++) {
            s16x8 af[2], bfr[4];
            #pragma unroll
            for (int m = 0; m < 2; m++)
                af[m] = *(const s16x8*)&lA[(w * 32 + m * 16 + l15) * 64 + ks * 32 + lg * 8];
            #pragma unroll
            for (int n = 0; n < 4; n++)
                bfr[n] = *(const s16x8*)&lB[(n * 16 + l15) * 64 + ks * 32 + lg * 8];
            #pragma unroll
            for (int m = 0; m < 2; m++)
                #pragma unroll
                for (int n = 0; n < 4; n++)
                    acc[m][n] = MFMA16(af[m], bfr[n], acc[m][n]);
        }
        __syncthreads();
    }
    #pragma unroll
    for (int m = 0; m < 2; m++)
        #pragma unroll
        for (int n = 0; n < 4; n++) {
            int col = n0 + n * 16 + l15;
            int row0 = m0 + w * 32 + m * 16 + lg * 4;
            #pragma unroll
            for (int r = 0; r < 4; r++)
                C[(size_t)(row0 + r) * N + col] = acc[m][n][r];
        }
}

// ---------------- fa/fc: per-k rel factors fa[g,k]=exp(ra.K[g,k]/8) ----------------
__global__ void k_fvec(const u16* __restrict__ Kb, const float* __restrict__ rel,
                       float* __restrict__ fa, float* __restrict__ fc) {
    __shared__ float rs[128];
    const int g = blockIdx.x, tid = threadIdx.x;
    if (tid < 128) rs[tid] = rel[tid];
    __syncthreads();
    for (int k = tid; k < 1024; k += 256) {
        const u16* kr = Kb + (size_t)g * 65536 + (size_t)k * 64;
        float sa = 0.f, sc = 0.f;
        #pragma unroll
        for (int j = 0; j < 8; j++) {
            s16x8 v = *(const s16x8*)(kr + j * 8);
            #pragma unroll
            for (int e = 0; e < 8; e++) {
                float kv = b2f((u16)v[e]);
                sa += kv * rs[j * 8 + e];
                sc += kv * rs[64 + j * 8 + e];
            }
        }
        fa[g * 1024 + k] = __expf(sa * 0.125f);
        fc[g * 1024 + k] = __expf(sc * 0.125f);
    }
}

// ---------------- E0 = exp(QK^T/8) bf16 row-major + denominators la,lc ----------------
// Single QK^T (rel-factorization). grid 1024 (XCD-swizzled), 4 waves.
__global__ __launch_bounds__(256, 2) void k_qke0(const u16* __restrict__ Qb, const u16* __restrict__ Kb,
                                                 const float* __restrict__ fa, const float* __restrict__ fc,
                                                 u16* __restrict__ E0,
                                                 float* __restrict__ la_, float* __restrict__ lc_) {
    const int bid = blockIdx.x;
    const int xcd = bid & 7, j = bid >> 3;
    const int g = xcd * 8 + (j & 7), qt = j >> 3;
    const int tid = threadIdx.x, lane = tid & 63, w = tid >> 6;
    const int l15 = lane & 15, lg = lane >> 4;
    __shared__ __align__(16) float lE[4][16][68];

    const int q0 = qt * 64 + w * 16;
    const size_t gQ = (size_t)g * 65536;
    const float scale = 0.125f;

    s16x8 qf[2];
    #pragma unroll
    for (int ks = 0; ks < 2; ks++)
        qf[ks] = *(const s16x8*)(Qb + gQ + (size_t)(q0 + l15) * 64 + ks * 32 + lg * 8);

    float la[4] = {0.f, 0.f, 0.f, 0.f}, lc[4] = {0.f, 0.f, 0.f, 0.f};
    const int srow = lane >> 2, sjj = lane & 3;  // store-phase mapping

    #pragma unroll 1
    for (int it = 0; it < 16; it++) {
        const int kb = it * 64;
        f32x4 sa[4] = {};
        s16x8 kf[8];
        #pragma unroll
        for (int ks = 0; ks < 2; ks++)
            #pragma unroll
            for (int n = 0; n < 4; n++)
                kf[ks * 4 + n] = *(const s16x8*)(Kb + gQ + (size_t)(kb + n * 16 + l15) * 64 + ks * 32 + lg * 8);
        #pragma unroll
        for (int ks = 0; ks < 2; ks++)
            #pragma unroll
            for (int n = 0; n < 4; n++)
                sa[n] = MFMA16(qf[ks], kf[ks * 4 + n], sa[n]);
        #pragma unroll
        for (int n = 0; n < 4; n++) {
            float fav = fa[g * 1024 + kb + n * 16 + l15];
            float fcv = fc[g * 1024 + kb + n * 16 + l15];
            #pragma unroll
            for (int r = 0; r < 4; r++) {
                float er = b2f(f2b(__expf(sa[n][r] * scale)));  // bf16-rounded, consistent w/ stored E0
                la[r] += er * fav;
                lc[r] += er * fcv;
                lE[w][lg * 4 + r][n * 16 + l15] = er;
            }
        }
        // coalesced row-major store: lane -> row=lane>>2, cols (lane&3)*16..+15
        {
            const float* lp = &lE[w][srow][sjj * 16];
            uint4 p0, p1;
            p0.x = (u32)f2b(lp[0]) | ((u32)f2b(lp[1]) << 16);
            p0.y = (u32)f2b(lp[2]) | ((u32)f2b(lp[3]) << 16);
            p0.z = (u32)f2b(lp[4]) | ((u32)f2b(lp[5]) << 16);
            p0.w = (u32)f2b(lp[6]) | ((u32)f2b(lp[7]) << 16);
            p1.x = (u32)f2b(lp[8]) | ((u32)f2b(lp[9]) << 16);
            p1.y = (u32)f2b(lp[10]) | ((u32)f2b(lp[11]) << 16);
            p1.z = (u32)f2b(lp[12]) | ((u32)f2b(lp[13]) << 16);
            p1.w = (u32)f2b(lp[14]) | ((u32)f2b(lp[15]) << 16);
            u16* ep = E0 + (size_t)g * 1048576 + (size_t)(q0 + srow) * 1024 + kb + sjj * 16;
            *(uint4*)ep = p0;
            *(uint4*)(ep + 8) = p1;
        }
    }
    #pragma unroll
    for (int r = 0; r < 4; r++)
        #pragma unroll
        for (int m = 8; m >= 1; m >>= 1) {
            la[r] += __shfl_xor(la[r], m);
            lc[r] += __shfl_xor(lc[r], m);
        }
    if (l15 == 0) {
        #pragma unroll
        for (int r = 0; r < 4; r++) {
            la_[g * 1024 + q0 + lg * 4 + r] = la[r];
            lc_[g * 1024 + q0 + lg * 4 + r] = lc[r];
        }
    }
}

// ---------------- P = E0 .* (fa.*Ma/la + fc.*Mc/lc)  — pure elementwise stream ----------------
// One 8-elem item per thread; no loop, no LDS, no MFMA -> k_f2b-class streaming.
__global__ void k_pmul(const u16* __restrict__ E0, const float* __restrict__ Ma, const float* __restrict__ Mc,
                       const float* __restrict__ fa, const float* __restrict__ fc,
                       const float* __restrict__ la, const float* __restrict__ lc,
                       u16* __restrict__ P) {
    int idx = blockIdx.x * 256 + threadIdx.x;  // 8M items
    int g = idx >> 17;
    int q = (idx >> 7) & 1023;
    int k0 = (idx & 127) * 8;
    size_t base = (size_t)idx * 8;
    s16x8 e = *(const s16x8*)(E0 + base);
    float4 m0 = *(const float4*)(Ma + base), m1 = *(const float4*)(Ma + base + 4);
    float4 n0 = *(const float4*)(Mc + base), n1 = *(const float4*)(Mc + base + 4);
    int fi = g * 1024 + k0;
    float4 a0 = *(const float4*)(fa + fi), a1 = *(const float4*)(fa + fi + 4);
    float4 c0 = *(const float4*)(fc + fi), c1 = *(const float4*)(fc + fi + 4);
    float ila = 1.f / la[g * 1024 + q];
    float ilc = 1.f / lc[g * 1024 + q];
    uint4 o;
    o.x = (u32)f2b(b2f((u16)e[0]) * (a0.x * m0.x * ila + c0.x * n0.x * ilc)) |
          ((u32)f2b(b2f((u16)e[1]) * (a0.y * m0.y * ila + c0.y * n0.y * ilc)) << 16);
    o.y = (u32)f2b(b2f((u16)e[2]) * (a0.z * m0.z * ila + c0.z * n0.z * ilc)) |
          ((u32)f2b(b2f((u16)e[3]) * (a0.w * m0.w * ila + c0.w * n0.w * ilc)) << 16);
    o.z = (u32)f2b(b2f((u16)e[4]) * (a1.x * m1.x * ila + c1.x * n1.x * ilc)) |
          ((u32)f2b(b2f((u16)e[5]) * (a1.y * m1.y * ila + c1.y * n1.y * ilc)) << 16);
    o.w = (u32)f2b(b2f((u16)e[6]) * (a1.z * m1.z * ila + c1.z * n1.z * ilc)) |
          ((u32)f2b(b2f((u16)e[7]) * (a1.w * m1.w * ila + c1.w * n1.w * ilc)) << 16);
    *(uint4*)(P + base) = o;
}

// ---------------- batched PV GEMM: ctx[g] = P[g] @ Vt[g]^T, bf16 out ----------------
__global__ __launch_bounds__(256) void gemm_pv(const u16* __restrict__ P, const u16* __restrict__ Vt,
                                               u16* __restrict__ ctx) {
    __shared__ __align__(16) short lA[128 * 64];
    __shared__ __align__(16) short lB[64 * 64];
    const int tid = threadIdx.x, lane = tid & 63, w = tid >> 6;
    const int l15 = lane & 15, lg = lane >> 4;
    const int g = blockIdx.y, m0 = blockIdx.x * 128;
    const u16* A = P + (size_t)g * 1048576;    // [1024,1024]
    const u16* Bt = Vt + (size_t)g * 65536;    // [64,1024]
    f32x4 acc[2][4] = {};

    for (int k0 = 0; k0 < 1024; k0 += 64) {
        #pragma unroll
        for (int i = 0; i < 4; i++) {
            int chunk = w * 4 + i;
            int arow = m0 + chunk * 8 + (lane >> 3);
            GLDS(A + (size_t)arow * 1024 + k0 + (lane & 7) * 8, (short*)lA + chunk * 512);
        }
        #pragma unroll
        for (int i = 0; i < 2; i++) {
            int chunk = w * 2 + i;
            int brow = chunk * 8 + (lane >> 3);
            GLDS(Bt + (size_t)brow * 1024 + k0 + (lane & 7) * 8, (short*)lB + chunk * 512);
        }
        __syncthreads();
        #pragma unroll
        for (int ks = 0; ks < 2; ks++) {
            s16x8 af[2], bfr[4];
            #pragma unroll
            for (int m = 0; m < 2; m++)
                af[m] = *(const s16x8*)&lA[(w * 32 + m * 16 + l15) * 64 + ks * 32 + lg * 8];
            #pragma unroll
            for (int n = 0; n < 4; n++)
                bfr[n] = *(const s16x8*)&lB[(n * 16 + l15) * 64 + ks * 32 + lg * 8];
            #pragma unroll
            for (int m = 0; m < 2; m++)
                #pragma unroll
                for (int n = 0; n < 4; n++)
                    acc[m][n] = MFMA16(af[m], bfr[n], acc[m][n]);
        }
        __syncthreads();
    }
    #pragma unroll
    for (int m = 0; m < 2; m++)
        #pragma unroll
        for (int n = 0; n < 4; n++) {
            int col = n * 16 + l15;
            int row0 = m0 + w * 32 + m * 16 + lg * 4;
            #pragma unroll
            for (int r = 0; r < 4; r++)
                ctx[(size_t)g * 65536 + (size_t)(row0 + r) * 64 + col] = f2b(acc[m][n][r]);
        }
}

// ---------------- row LayerNorm ----------------
__global__ __launch_bounds__(256) void k_ln(const float* __restrict__ a, const float* __restrict__ bias,
                                            const float* __restrict__ resid, const float* __restrict__ gamma,
                                            const float* __restrict__ beta, float* __restrict__ out,
                                            u16* __restrict__ outb) {
    const int row = blockIdx.x, tid = threadIdx.x;
    const size_t base = (size_t)row * 1024 + tid * 4;
    float4 av = *(const float4*)(a + base);
    float4 rv = *(const float4*)(resid + base);
    float4 bv = *(const float4*)(bias + tid * 4);
    float t0 = av.x + rv.x + bv.x, t1 = av.y + rv.y + bv.y;
    float t2 = av.z + rv.z + bv.z, t3 = av.w + rv.w + bv.w;
    __shared__ float red[4];
    float s = t0 + t1 + t2 + t3;
    #pragma unroll
    for (int m = 32; m >= 1; m >>= 1) s += __shfl_xor(s, m);
    int w = tid >> 6;
    if ((tid & 63) == 0) red[w] = s;
    __syncthreads();
    float mean = (red[0] + red[1] + red[2] + red[3]) * (1.f / 1024.f);
    float d0 = t0 - mean, d1 = t1 - mean, d2 = t2 - mean, d3 = t3 - mean;
    float q = d0 * d0 + d1 * d1 + d2 * d2 + d3 * d3;
    __syncthreads();
    #pragma unroll
    for (int m = 32; m >= 1; m >>= 1) q += __shfl_xor(q, m);
    if ((tid & 63) == 0) red[w] = q;
    __syncthreads();
    float var = (red[0] + red[1] + red[2] + red[3]) * (1.f / 1024.f);
    float rs = rsqrtf(var + 1e-5f);
    float4 gv = *(const float4*)(gamma + tid * 4);
    float4 bev = *(const float4*)(beta + tid * 4);
    float o0 = d0 * rs * gv.x + bev.x, o1 = d1 * rs * gv.y + bev.y;
    float o2 = d2 * rs * gv.z + bev.z, o3 = d3 * rs * gv.w + bev.w;
    *(float4*)(out + base) = make_float4(o0, o1, o2, o3);
    if (outb) {
        ushort4 ob;
        ob.x = f2b(o0); ob.y = f2b(o1); ob.z = f2b(o2); ob.w = f2b(o3);
        *(ushort4*)(outb + base) = ob;
    }
}

extern "C" void kernel_launch(void* const* d_in, const int* in_sizes, int n_in,
                              void* d_out, int out_size, void* d_ws, size_t ws_size,
                              hipStream_t stream) {
    const float* x    = (const float*)d_in[0];
    const float* adjm = (const float*)d_in[1];
    const float* comm = (const float*)d_in[2];
    const float* rel  = (const float*)d_in[3];
    const float* Wq   = (const float*)d_in[4];
    const float* bq   = (const float*)d_in[5];
    const float* Wk   = (const float*)d_in[6];
    const float* bk   = (const float*)d_in[7];
    const float* Wv   = (const float*)d_in[8];
    const float* bv   = (const float*)d_in[9];
    const float* Wo   = (const float*)d_in[10];
    const float* bo   = (const float*)d_in[11];
    const float* g1   = (const float*)d_in[12];
    const float* be1  = (const float*)d_in[13];
    const float* W1   = (const float*)d_in[14];
    const float* b1   = (const float*)d_in[15];
    const float* W2   = (const float*)d_in[16];
    const float* b2   = (const float*)d_in[17];
    const float* g2   = (const float*)d_in[18];
    const float* be2  = (const float*)d_in[19];
    float* out = (float*)d_out;

    char* ws = (char*)d_ws;
    const size_t MB = 1048576;
    u16*   xb    = (u16*)(ws + 0 * MB);      // 8 MiB (dead after gemm_qkv)
    u16*   Wqkvt = (u16*)(ws + 8 * MB);      // 6 MiB
    u16*   Wot   = (u16*)(ws + 14 * MB);     // 2 MiB
    u16*   W1t   = (u16*)(ws + 16 * MB);     // 8 MiB
    u16*   W2t   = (u16*)(ws + 24 * MB);     // 8 MiB (live through FFN2)
    u16*   Qb    = (u16*)(ws + 32 * MB);     // 8 MiB
    u16*   Kb    = (u16*)(ws + 40 * MB);     // 8 MiB
    u16*   Vtb   = (u16*)(ws + 48 * MB);     // 8 MiB
    float* faB   = (float*)(ws + 56 * MB);   // 256 KiB each: fa, fc, la, lc
    float* fcB   = (float*)(ws + 56 * MB + 262144);
    float* laB   = (float*)(ws + 56 * MB + 524288);
    float* lcB   = (float*)(ws + 56 * MB + 786432);
    u16*   E0b   = (u16*)(ws + 57 * MB);     // 128 MiB [57,185)
    u16*   Pb    = (u16*)(ws + 185 * MB);    // 128 MiB [185,313)
    u16*   ctx   = (u16*)(ws + 313 * MB);    // 8 MiB
    float* ctxWo = (float*)(ws + 57 * MB);   // 16 MiB reuse E0 (dead after pmul)
    float* out1  = (float*)(ws + 73 * MB);   // 16 MiB reuse E0 (live to LN2)
    u16*   out1b = (u16*)(ws + 89 * MB);     // 8 MiB reuse E0
    u16*   rb    = (u16*)(ws + 97 * MB);     // 32 MiB reuse E0 (FFN1 out)
    float* ff2   = (float*)(ws + 129 * MB);  // 16 MiB reuse E0

    dim3 tb(32, 8);
    // 1. casts / weight prep
    k_f2b<<<4096, 256, 0, stream>>>(x, xb, 1048576);
    k_wtrans<<<dim3(32, 32), tb, 0, stream>>>(Wq, Wqkvt, 1024, 1024);
    k_wtrans<<<dim3(32, 32), tb, 0, stream>>>(Wk, Wqkvt + 1024 * 1024, 1024, 1024);
    k_wtrans<<<dim3(32, 32), tb, 0, stream>>>(Wv, Wqkvt + 2 * 1024 * 1024, 1024, 1024);
    k_wtrans<<<dim3(32, 32), tb, 0, stream>>>(Wo, Wot, 1024, 1024);
    k_wtrans<<<dim3(128, 32), tb, 0, stream>>>(W1, W1t, 1024, 4096);
    k_wtrans<<<dim3(32, 128), tb, 0, stream>>>(W2, W2t, 4096, 1024);
    // 2. fused QKV projection (plain Q,K + transposed V)
    gemm_qkv<<<dim3(24, 32), 256, 0, stream>>>(xb, Wqkvt, bq, bk, bv, Qb, Kb, Vtb);
    // 3. attention via softmax factorization
    k_fvec<<<64, 256, 0, stream>>>(Kb, rel, faB, fcB);
    k_qke0<<<1024, 256, 0, stream>>>(Qb, Kb, faB, fcB, E0b, laB, lcB);
    k_pmul<<<32768, 256, 0, stream>>>(E0b, adjm, comm, faB, fcB, laB, lcB, Pb);
    gemm_pv<<<dim3(8, 64), 256, 0, stream>>>(Pb, Vtb, ctx);
    // 4. output projection + LN1
    gemm_bt64<<<dim3(16, 32), 256, 0, stream>>>(ctx, Wot, ctxWo, 4096, 1024, 1024);
    k_ln<<<4096, 256, 0, stream>>>(ctxWo, bo, x, g1, be1, out1, out1b);
    // 5. FFN
    gemm_bt<1><<<dim3(32, 32), 256, 0, stream>>>(out1b, W1t, rb, 4096, 4096, 1024, b1);
    gemm_bt64<<<dim3(16, 32), 256, 0, stream>>>(rb, W2t, ff2, 4096, 1024, 4096);
    // 6. LN2 -> final output
    k_ln<<<4096, 256, 0, stream>>>(ff2, b2, out1, g2, be2, out, nullptr);
}

// Round 13
// 561.989 us; speedup vs baseline: 1.1941x; 1.0009x over previous
//
#include <hip/hip_runtime.h>
#include <hip/hip_bf16.h>

typedef __attribute__((ext_vector_type(8))) short s16x8;
typedef __attribute__((ext_vector_type(4))) float f32x4;
typedef unsigned short u16;
typedef unsigned int u32;

__device__ __forceinline__ u16 f2b(float f) {
    u32 u = __float_as_uint(f);
    u32 r = (u + 0x7fffu + ((u >> 16) & 1u)) >> 16;  // RNE bf16
    return (u16)r;
}
__device__ __forceinline__ float b2f(u16 b) {
    return __uint_as_float(((u32)b) << 16);
}

#define MFMA16(a, b, c) __builtin_amdgcn_mfma_f32_16x16x32_bf16(a, b, c, 0, 0, 0)
#define GLDS(gp, lp)                                                              \
    __builtin_amdgcn_global_load_lds((const __attribute__((address_space(1))) void*)(gp), \
                                     (__attribute__((address_space(3))) void*)(lp), 16, 0, 0)

// ---------------- elementwise: f32 -> bf16 ----------------
__global__ void k_f2b(const float* __restrict__ in, u16* __restrict__ out, int n4) {
    int i = blockIdx.x * 256 + threadIdx.x;
    if (i >= n4) return;
    float4 v = ((const float4*)in)[i];
    ushort4 o;
    o.x = f2b(v.x); o.y = f2b(v.y); o.z = f2b(v.z); o.w = f2b(v.w);
    ((ushort4*)out)[i] = o;
}

// ---------------- weight transpose+convert: W[K,N] f32 -> Wt[N,K] bf16 ----------------
__global__ void k_wtrans(const float* __restrict__ W, u16* __restrict__ Wt, int K, int N) {
    __shared__ float t[32][33];
    int bx = blockIdx.x * 32, by = blockIdx.y * 32;
    int tx = threadIdx.x, ty = threadIdx.y;
    for (int i = 0; i < 32; i += 8)
        t[ty + i][tx] = W[(size_t)(by + ty + i) * N + bx + tx];
    __syncthreads();
    for (int i = 0; i < 32; i += 8)
        Wt[(size_t)(bx + ty + i) * K + by + tx] = f2b(t[tx][ty + i]);
}

// ---------------- fused QKV GEMM: epilogue writes Qb/Kb (bias only) + transposed Vt ----------------
__global__ __launch_bounds__(256) void gemm_qkv(const u16* __restrict__ A, const u16* __restrict__ Bt,
                                                const float* __restrict__ bq, const float* __restrict__ bk,
                                                const float* __restrict__ bv,
                                                u16* __restrict__ Qb, u16* __restrict__ Kb,
                                                u16* __restrict__ Vt) {
    __shared__ __align__(16) short lA[128 * 64];
    __shared__ __align__(16) short lB[128 * 64];
    const int tid = threadIdx.x, lane = tid & 63, w = tid >> 6;
    const int l15 = lane & 15, lg = lane >> 4;
    const int wr = w >> 1, wc = w & 1;
    const int m0 = blockIdx.y * 128, n0 = blockIdx.x * 128;
    const int KK = 1024;
    f32x4 acc[4][4] = {};

    for (int k0 = 0; k0 < KK; k0 += 64) {
        #pragma unroll
        for (int i = 0; i < 4; i++) {
            int chunk = w * 4 + i;
            int arow = m0 + chunk * 8 + (lane >> 3);
            GLDS(A + (size_t)arow * KK + k0 + (lane & 7) * 8, (short*)lA + chunk * 512);
            int brow = n0 + chunk * 8 + (lane >> 3);
            GLDS(Bt + (size_t)brow * KK + k0 + (lane & 7) * 8, (short*)lB + chunk * 512);
        }
        __syncthreads();
        #pragma unroll
        for (int ks = 0; ks < 2; ks++) {
            s16x8 af[4], bfr[4];
            #pragma unroll
            for (int m = 0; m < 4; m++)
                af[m] = *(const s16x8*)&lA[(wr * 64 + m * 16 + l15) * 64 + ks * 32 + lg * 8];
            #pragma unroll
            for (int n = 0; n < 4; n++)
                bfr[n] = *(const s16x8*)&lB[(wc * 64 + n * 16 + l15) * 64 + ks * 32 + lg * 8];
            #pragma unroll
            for (int m = 0; m < 4; m++)
                #pragma unroll
                for (int n = 0; n < 4; n++)
                    acc[m][n] = MFMA16(af[m], bfr[n], acc[m][n]);
        }
        __syncthreads();
    }
    const int rbase = m0 + wr * 64, cbase = n0 + wc * 64;
    const int seg = cbase >> 10;
    #pragma unroll
    for (int m = 0; m < 4; m++)
        #pragma unroll
        for (int n = 0; n < 4; n++) {
            int col = cbase + n * 16 + l15;
            int c1 = col & 1023, d = col & 63;
            int row0 = rbase + m * 16 + lg * 4;
            if (seg == 0) {
                float bb = bq[c1];
                #pragma unroll
                for (int r = 0; r < 4; r++)
                    Qb[(size_t)(row0 + r) * 1024 + c1] = f2b(acc[m][n][r] + bb);
            } else if (seg == 1) {
                float bb = bk[c1];
                #pragma unroll
                for (int r = 0; r < 4; r++)
                    Kb[(size_t)(row0 + r) * 1024 + c1] = f2b(acc[m][n][r] + bb);
            } else {
                float bb = bv[c1];
                #pragma unroll
                for (int r = 0; r < 4; r++) {
                    int row = row0 + r;
                    size_t o = (size_t)(row >> 6) * 65536 + (size_t)d * 1024 + (row & 63) * 16 + (c1 >> 6);
                    Vt[o] = f2b(acc[m][n][r] + bb);
                }
            }
        }
}

// ---------------- GEMM 128x128, EPI 1: bf16(relu(acc+bias)) ----------------
template <int EPI>
__global__ __launch_bounds__(256) void gemm_bt(const u16* __restrict__ A, const u16* __restrict__ Bt,
                                               void* __restrict__ Cv, int M, int N, int K,
                                               const float* __restrict__ bias) {
    __shared__ __align__(16) short lA[128 * 64];
    __shared__ __align__(16) short lB[128 * 64];
    const int tid = threadIdx.x, lane = tid & 63, w = tid >> 6;
    const int l15 = lane & 15, lg = lane >> 4;
    const int wr = w >> 1, wc = w & 1;
    const int m0 = blockIdx.y * 128, n0 = blockIdx.x * 128;
    f32x4 acc[4][4] = {};

    for (int k0 = 0; k0 < K; k0 += 64) {
        #pragma unroll
        for (int i = 0; i < 4; i++) {
            int chunk = w * 4 + i;
            int arow = m0 + chunk * 8 + (lane >> 3);
            GLDS(A + (size_t)arow * K + k0 + (lane & 7) * 8, (short*)lA + chunk * 512);
            int brow = n0 + chunk * 8 + (lane >> 3);
            GLDS(Bt + (size_t)brow * K + k0 + (lane & 7) * 8, (short*)lB + chunk * 512);
        }
        __syncthreads();
        #pragma unroll
        for (int ks = 0; ks < 2; ks++) {
            s16x8 af[4], bfr[4];
            #pragma unroll
            for (int m = 0; m < 4; m++)
                af[m] = *(const s16x8*)&lA[(wr * 64 + m * 16 + l15) * 64 + ks * 32 + lg * 8];
            #pragma unroll
            for (int n = 0; n < 4; n++)
                bfr[n] = *(const s16x8*)&lB[(wc * 64 + n * 16 + l15) * 64 + ks * 32 + lg * 8];
            #pragma unroll
            for (int m = 0; m < 4; m++)
                #pragma unroll
                for (int n = 0; n < 4; n++)
                    acc[m][n] = MFMA16(af[m], bfr[n], acc[m][n]);
        }
        __syncthreads();
    }
    const int rbase = m0 + wr * 64, cbase = n0 + wc * 64;
    #pragma unroll
    for (int m = 0; m < 4; m++)
        #pragma unroll
        for (int n = 0; n < 4; n++) {
            int col = cbase + n * 16 + l15;
            int row0 = rbase + m * 16 + lg * 4;
            u16* C = (u16*)Cv;
            float bv = bias[col];
            #pragma unroll
            for (int r = 0; r < 4; r++)
                C[(size_t)(row0 + r) * N + col] = f2b(fmaxf(acc[m][n][r] + bv, 0.f));
        }
}

// ---------------- GEMM 128x64 f32-out ----------------
__global__ __launch_bounds__(256) void gemm_bt64(const u16* __restrict__ A, const u16* __restrict__ Bt,
                                                 float* __restrict__ C, int M, int N, int K) {
    __shared__ __align__(16) short lA[128 * 64];
    __shared__ __align__(16) short lB[64 * 64];
    const int tid = threadIdx.x, lane = tid & 63, w = tid >> 6;
    const int l15 = lane & 15, lg = lane >> 4;
    const int m0 = blockIdx.y * 128, n0 = blockIdx.x * 64;
    f32x4 acc[2][4] = {};

    for (int k0 = 0; k0 < K; k0 += 64) {
        #pragma unroll
        for (int i = 0; i < 4; i++) {
            int chunk = w * 4 + i;
            int arow = m0 + chunk * 8 + (lane >> 3);
            GLDS(A + (size_t)arow * K + k0 + (lane & 7) * 8, (short*)lA + chunk * 512);
        }
        #pragma unroll
        for (int i = 0; i < 2; i++) {
            int chunk = w * 2 + i;
            int brow = n0 + chunk * 8 + (lane >> 3);
            GLDS(Bt + (size_t)brow * K + k0 + (lane & 7) * 8, (short*)lB + chunk * 512);
        }
        __syncthreads();
        #pragma unroll
        for (int ks = 0; ks < 2; ks++) {
            s16x8 af[2], bfr[4];
            #pragma unroll
            for (int m = 0; m < 2; m++)
                af[m] = *(const s16x8*)&lA[(w * 32 + m * 16 + l15) * 64 + ks * 32 + lg * 8];
            #pragma unroll
            for (int n = 0; n < 4; n++)
                bfr[n] = *(const s16x8*)&lB[(n * 16 + l15) * 64 + ks * 32 + lg * 8];
            #pragma unroll
            for (int m = 0; m < 2; m++)
                #pragma unroll
                for (int n = 0; n < 4; n++)
                    acc[m][n] = MFMA16(af[m], bfr[n], acc[m][n]);
        }
        __syncthreads();
    }
    #pragma unroll
    for (int m = 0; m < 2; m++)
        #pragma unroll
        for (int n = 0; n < 4; n++) {
            int col = n0 + n * 16 + l15;
            int row0 = m0 + w * 32 + m * 16 + lg * 4;
            #pragma unroll
            for (int r = 0; r < 4; r++)
                C[(size_t)(row0 + r) * N + col] = acc[m][n][r];
        }
}

// ---------------- fa/fc: per-k rel factors fa[g,k]=exp(ra.K[g,k]/8) ----------------
__global__ void k_fvec(const u16* __restrict__ Kb, const float* __restrict__ rel,
                       float* __restrict__ fa, float* __restrict__ fc) {
    __shared__ float rs[128];
    const int g = blockIdx.x, tid = threadIdx.x;
    if (tid < 128) rs[tid] = rel[tid];
    __syncthreads();
    for (int k = tid; k < 1024; k += 256) {
        const u16* kr = Kb + (size_t)g * 65536 + (size_t)k * 64;
        float sa = 0.f, sc = 0.f;
        #pragma unroll
        for (int j = 0; j < 8; j++) {
            s16x8 v = *(const s16x8*)(kr + j * 8);
            #pragma unroll
            for (int e = 0; e < 8; e++) {
                float kv = b2f((u16)v[e]);
                sa += kv * rs[j * 8 + e];
                sc += kv * rs[64 + j * 8 + e];
            }
        }
        fa[g * 1024 + k] = __expf(sa * 0.125f);
        fc[g * 1024 + k] = __expf(sc * 0.125f);
    }
}

// ---------------- E0 = exp(QK^T/8) bf16 row-major + denominators la,lc ----------------
__global__ __launch_bounds__(256, 2) void k_qke0(const u16* __restrict__ Qb, const u16* __restrict__ Kb,
                                                 const float* __restrict__ fa, const float* __restrict__ fc,
                                                 u16* __restrict__ E0,
                                                 float* __restrict__ la_, float* __restrict__ lc_) {
    const int bid = blockIdx.x;
    const int xcd = bid & 7, j = bid >> 3;
    const int g = xcd * 8 + (j & 7), qt = j >> 3;
    const int tid = threadIdx.x, lane = tid & 63, w = tid >> 6;
    const int l15 = lane & 15, lg = lane >> 4;
    __shared__ __align__(16) float lE[4][16][68];

    const int q0 = qt * 64 + w * 16;
    const size_t gQ = (size_t)g * 65536;
    const float scale = 0.125f;

    s16x8 qf[2];
    #pragma unroll
    for (int ks = 0; ks < 2; ks++)
        qf[ks] = *(const s16x8*)(Qb + gQ + (size_t)(q0 + l15) * 64 + ks * 32 + lg * 8);

    float la[4] = {0.f, 0.f, 0.f, 0.f}, lc[4] = {0.f, 0.f, 0.f, 0.f};
    const int srow = lane >> 2, sjj = lane & 3;

    #pragma unroll 1
    for (int it = 0; it < 16; it++) {
        const int kb = it * 64;
        f32x4 sa[4] = {};
        s16x8 kf[8];
        #pragma unroll
        for (int ks = 0; ks < 2; ks++)
            #pragma unroll
            for (int n = 0; n < 4; n++)
                kf[ks * 4 + n] = *(const s16x8*)(Kb + gQ + (size_t)(kb + n * 16 + l15) * 64 + ks * 32 + lg * 8);
        #pragma unroll
        for (int ks = 0; ks < 2; ks++)
            #pragma unroll
            for (int n = 0; n < 4; n++)
                sa[n] = MFMA16(qf[ks], kf[ks * 4 + n], sa[n]);
        #pragma unroll
        for (int n = 0; n < 4; n++) {
            float fav = fa[g * 1024 + kb + n * 16 + l15];
            float fcv = fc[g * 1024 + kb + n * 16 + l15];
            #pragma unroll
            for (int r = 0; r < 4; r++) {
                float er = b2f(f2b(__expf(sa[n][r] * scale)));
                la[r] += er * fav;
                lc[r] += er * fcv;
                lE[w][lg * 4 + r][n * 16 + l15] = er;
            }
        }
        {
            const float* lp = &lE[w][srow][sjj * 16];
            uint4 p0, p1;
            p0.x = (u32)f2b(lp[0]) | ((u32)f2b(lp[1]) << 16);
            p0.y = (u32)f2b(lp[2]) | ((u32)f2b(lp[3]) << 16);
            p0.z = (u32)f2b(lp[4]) | ((u32)f2b(lp[5]) << 16);
            p0.w = (u32)f2b(lp[6]) | ((u32)f2b(lp[7]) << 16);
            p1.x = (u32)f2b(lp[8]) | ((u32)f2b(lp[9]) << 16);
            p1.y = (u32)f2b(lp[10]) | ((u32)f2b(lp[11]) << 16);
            p1.z = (u32)f2b(lp[12]) | ((u32)f2b(lp[13]) << 16);
            p1.w = (u32)f2b(lp[14]) | ((u32)f2b(lp[15]) << 16);
            u16* ep = E0 + (size_t)g * 1048576 + (size_t)(q0 + srow) * 1024 + kb + sjj * 16;
            *(uint4*)ep = p0;
            *(uint4*)(ep + 8) = p1;
        }
    }
    #pragma unroll
    for (int r = 0; r < 4; r++)
        #pragma unroll
        for (int m = 8; m >= 1; m >>= 1) {
            la[r] += __shfl_xor(la[r], m);
            lc[r] += __shfl_xor(lc[r], m);
        }
    if (l15 == 0) {
        #pragma unroll
        for (int r = 0; r < 4; r++) {
            la_[g * 1024 + q0 + lg * 4 + r] = la[r];
            lc_[g * 1024 + q0 + lg * 4 + r] = lc[r];
        }
    }
}

// ---------------- fused P-compute + PV GEMM ----------------
// Per block: one g, 64 q rows. Masks staged via GLDS (no VGPR dest -> full-tile MLP,
// the mechanism that makes gemm_bt stream). P computed in LDS, fed to MFMA. Replaces
// k_pmul + gemm_pv, deleting the 256 MB P round-trip.
__global__ __launch_bounds__(256) void gemm_pvf(const u16* __restrict__ E0, const u16* __restrict__ Vt,
                                                const float* __restrict__ Ma_g, const float* __restrict__ Mc_g,
                                                const float* __restrict__ fa, const float* __restrict__ fc,
                                                const float* __restrict__ la, const float* __restrict__ lc,
                                                u16* __restrict__ ctx) {
    __shared__ __align__(16) float bufMa[64 * 64];   // 16 KB
    __shared__ __align__(16) float bufMc[64 * 64];   // 16 KB
    __shared__ __align__(16) short bufP[64 * 68];    // 8.5 KB (padded rows: conflict-free frag reads)
    __shared__ __align__(16) short bufV[64 * 68];    // 8.5 KB
    __shared__ __align__(16) float lfa[1024];        // 4 KB
    __shared__ __align__(16) float lfc[1024];        // 4 KB

    const int bid = blockIdx.x;
    const int xcd = bid & 7, j = bid >> 3;
    const int g = xcd * 8 + (j & 7), qt = j >> 3;
    const int tid = threadIdx.x, lane = tid & 63, w = tid >> 6;
    const int l15 = lane & 15, lg = lane >> 4;
    const int q0 = qt * 64;
    const size_t gE = (size_t)g * 1048576;
    const size_t gV = (size_t)g * 65536;

    // preload fa/fc for this g (1 GLDS op per wave each), denominators per thread row
    GLDS(fa + g * 1024 + w * 256 + (lane & 63) * 4, lfa + w * 256);
    GLDS(fc + g * 1024 + w * 256 + (lane & 63) * 4, lfc + w * 256);
    const int pr = tid >> 2, pc = (tid & 3) * 16;   // P-compute assignment: row pr, cols pc..pc+15
    const float ila = 1.f / la[g * 1024 + q0 + pr];
    const float ilc = 1.f / lc[g * 1024 + q0 + pr];
    const int vd = tid >> 2, vc = (tid & 3) * 16;   // V staging: d-row vd, cols vc..vc+15

    f32x4 acc[4] = {};
    __syncthreads();  // lfa/lfc ready

    #pragma unroll 1
    for (int it = 0; it < 16; it++) {
        const int kb = it * 64;
        // --- GLDS mask tiles: 4 ops each per wave, 1 KB per op, no VGPR dest ---
        #pragma unroll
        for (int o = 0; o < 4; o++) {
            int op = w * 4 + o;
            int row = op * 4 + (lane >> 4);
            int ch = lane & 15;
            GLDS(Ma_g + (size_t)g * 1048576 + (size_t)(q0 + row) * 1024 + kb + ch * 4, bufMa + op * 256);
            GLDS(Mc_g + (size_t)g * 1048576 + (size_t)(q0 + row) * 1024 + kb + ch * 4, bufMc + op * 256);
        }
        // --- V tile to regs (L2-hot) + E0 rows to regs (overlap GLDS drain) ---
        s16x8 v0 = *(const s16x8*)(Vt + gV + (size_t)vd * 1024 + kb + vc);
        s16x8 v1 = *(const s16x8*)(Vt + gV + (size_t)vd * 1024 + kb + vc + 8);
        s16x8 e0 = *(const s16x8*)(E0 + gE + (size_t)(q0 + pr) * 1024 + kb + pc);
        s16x8 e1 = *(const s16x8*)(E0 + gE + (size_t)(q0 + pr) * 1024 + kb + pc + 8);
        *(s16x8*)&bufV[vd * 68 + vc] = v0;
        *(s16x8*)&bufV[vd * 68 + vc + 8] = v1;
        __syncthreads();  // masks + V staged
        // --- P-compute: P = E0 .* (fa.*Ma/la + fc.*Mc/lc) ---
        {
            const float* map = &bufMa[pr * 64 + pc];
            const float* mcp = &bufMc[pr * 64 + pc];
            const float* fap = &lfa[kb + pc];
            const float* fcp = &lfc[kb + pc];
            union { s16x8 v; u16 u[8]; } o0, o1;
            #pragma unroll
            for (int e = 0; e < 8; e++) {
                float t = fap[e] * map[e] * ila + fcp[e] * mcp[e] * ilc;
                o0.u[e] = f2b(b2f((u16)e0[e]) * t);
            }
            #pragma unroll
            for (int e = 0; e < 8; e++) {
                float t = fap[8 + e] * map[8 + e] * ila + fcp[8 + e] * mcp[8 + e] * ilc;
                o1.u[e] = f2b(b2f((u16)e1[e]) * t);
            }
            *(s16x8*)&bufP[pr * 68 + pc] = o0.v;
            *(s16x8*)&bufP[pr * 68 + pc + 8] = o1.v;
        }
        __syncthreads();  // P ready
        // --- MFMA: wave w computes ctx rows w*16..+15 ---
        #pragma unroll
        for (int ks = 0; ks < 2; ks++) {
            s16x8 af = *(const s16x8*)&bufP[(w * 16 + l15) * 68 + ks * 32 + lg * 8];
            #pragma unroll
            for (int n = 0; n < 4; n++) {
                s16x8 bfr = *(const s16x8*)&bufV[(n * 16 + l15) * 68 + ks * 32 + lg * 8];
                acc[n] = MFMA16(af, bfr, acc[n]);
            }
        }
        __syncthreads();  // protect buffers before next stage
    }
    #pragma unroll
    for (int n = 0; n < 4; n++) {
        int col = n * 16 + l15;
        int row0 = q0 + w * 16 + lg * 4;
        #pragma unroll
        for (int r = 0; r < 4; r++)
            ctx[gV + (size_t)(row0 + r) * 64 + col] = f2b(acc[n][r]);
    }
}

// ---------------- row LayerNorm ----------------
__global__ __launch_bounds__(256) void k_ln(const float* __restrict__ a, const float* __restrict__ bias,
                                            const float* __restrict__ resid, const float* __restrict__ gamma,
                                            const float* __restrict__ beta, float* __restrict__ out,
                                            u16* __restrict__ outb) {
    const int row = blockIdx.x, tid = threadIdx.x;
    const size_t base = (size_t)row * 1024 + tid * 4;
    float4 av = *(const float4*)(a + base);
    float4 rv = *(const float4*)(resid + base);
    float4 bv = *(const float4*)(bias + tid * 4);
    float t0 = av.x + rv.x + bv.x, t1 = av.y + rv.y + bv.y;
    float t2 = av.z + rv.z + bv.z, t3 = av.w + rv.w + bv.w;
    __shared__ float red[4];
    float s = t0 + t1 + t2 + t3;
    #pragma unroll
    for (int m = 32; m >= 1; m >>= 1) s += __shfl_xor(s, m);
    int w = tid >> 6;
    if ((tid & 63) == 0) red[w] = s;
    __syncthreads();
    float mean = (red[0] + red[1] + red[2] + red[3]) * (1.f / 1024.f);
    float d0 = t0 - mean, d1 = t1 - mean, d2 = t2 - mean, d3 = t3 - mean;
    float q = d0 * d0 + d1 * d1 + d2 * d2 + d3 * d3;
    __syncthreads();
    #pragma unroll
    for (int m = 32; m >= 1; m >>= 1) q += __shfl_xor(q, m);
    if ((tid & 63) == 0) red[w] = q;
    __syncthreads();
    float var = (red[0] + red[1] + red[2] + red[3]) * (1.f / 1024.f);
    float rs = rsqrtf(var + 1e-5f);
    float4 gv = *(const float4*)(gamma + tid * 4);
    float4 bev = *(const float4*)(beta + tid * 4);
    float o0 = d0 * rs * gv.x + bev.x, o1 = d1 * rs * gv.y + bev.y;
    float o2 = d2 * rs * gv.z + bev.z, o3 = d3 * rs * gv.w + bev.w;
    *(float4*)(out + base) = make_float4(o0, o1, o2, o3);
    if (outb) {
        ushort4 ob;
        ob.x = f2b(o0); ob.y = f2b(o1); ob.z = f2b(o2); ob.w = f2b(o3);
        *(ushort4*)(outb + base) = ob;
    }
}

extern "C" void kernel_launch(void* const* d_in, const int* in_sizes, int n_in,
                              void* d_out, int out_size, void* d_ws, size_t ws_size,
                              hipStream_t stream) {
    const float* x    = (const float*)d_in[0];
    const float* adjm = (const float*)d_in[1];
    const float* comm = (const float*)d_in[2];
    const float* rel  = (const float*)d_in[3];
    const float* Wq   = (const float*)d_in[4];
    const float* bq   = (const float*)d_in[5];
    const float* Wk   = (const float*)d_in[6];
    const float* bk   = (const float*)d_in[7];
    const float* Wv   = (const float*)d_in[8];
    const float* bv   = (const float*)d_in[9];
    const float* Wo   = (const float*)d_in[10];
    const float* bo   = (const float*)d_in[11];
    const float* g1   = (const float*)d_in[12];
    const float* be1  = (const float*)d_in[13];
    const float* W1   = (const float*)d_in[14];
    const float* b1   = (const float*)d_in[15];
    const float* W2   = (const float*)d_in[16];
    const float* b2   = (const float*)d_in[17];
    const float* g2   = (const float*)d_in[18];
    const float* be2  = (const float*)d_in[19];
    float* out = (float*)d_out;

    char* ws = (char*)d_ws;
    const size_t MB = 1048576;
    u16*   xb    = (u16*)(ws + 0 * MB);      // 8 MiB (dead after gemm_qkv)
    u16*   Wqkvt = (u16*)(ws + 8 * MB);      // 6 MiB
    u16*   Wot   = (u16*)(ws + 14 * MB);     // 2 MiB
    u16*   W1t   = (u16*)(ws + 16 * MB);     // 8 MiB
    u16*   W2t   = (u16*)(ws + 24 * MB);     // 8 MiB (live through FFN2)
    u16*   Qb    = (u16*)(ws + 32 * MB);     // 8 MiB
    u16*   Kb    = (u16*)(ws + 40 * MB);     // 8 MiB
    u16*   Vtb   = (u16*)(ws + 48 * MB);     // 8 MiB
    float* faB   = (float*)(ws + 56 * MB);   // 256 KiB each: fa, fc, la, lc
    float* fcB   = (float*)(ws + 56 * MB + 262144);
    float* laB   = (float*)(ws + 56 * MB + 524288);
    float* lcB   = (float*)(ws + 56 * MB + 786432);
    u16*   E0b   = (u16*)(ws + 57 * MB);     // 128 MiB [57,185)
    u16*   ctx   = (u16*)(ws + 185 * MB);    // 8 MiB
    float* ctxWo = (float*)(ws + 193 * MB);  // 16 MiB
    float* out1  = (float*)(ws + 209 * MB);  // 16 MiB (live to LN2)
    u16*   out1b = (u16*)(ws + 225 * MB);    // 8 MiB
    u16*   rb    = (u16*)(ws + 233 * MB);    // 32 MiB (FFN1 out)
    float* ff2   = (float*)(ws + 265 * MB);  // 16 MiB

    dim3 tb(32, 8);
    // 1. casts / weight prep
    k_f2b<<<4096, 256, 0, stream>>>(x, xb, 1048576);
    k_wtrans<<<dim3(32, 32), tb, 0, stream>>>(Wq, Wqkvt, 1024, 1024);
    k_wtrans<<<dim3(32, 32), tb, 0, stream>>>(Wk, Wqkvt + 1024 * 1024, 1024, 1024);
    k_wtrans<<<dim3(32, 32), tb, 0, stream>>>(Wv, Wqkvt + 2 * 1024 * 1024, 1024, 1024);
    k_wtrans<<<dim3(32, 32), tb, 0, stream>>>(Wo, Wot, 1024, 1024);
    k_wtrans<<<dim3(128, 32), tb, 0, stream>>>(W1, W1t, 1024, 4096);
    k_wtrans<<<dim3(32, 128), tb, 0, stream>>>(W2, W2t, 4096, 1024);
    // 2. fused QKV projection (plain Q,K + transposed V)
    gemm_qkv<<<dim3(24, 32), 256, 0, stream>>>(xb, Wqkvt, bq, bk, bv, Qb, Kb, Vtb);
    // 3. attention via softmax factorization + fused mask-PV
    k_fvec<<<64, 256, 0, stream>>>(Kb, rel, faB, fcB);
    k_qke0<<<1024, 256, 0, stream>>>(Qb, Kb, faB, fcB, E0b, laB, lcB);
    gemm_pvf<<<1024, 256, 0, stream>>>(E0b, Vtb, adjm, comm, faB, fcB, laB, lcB, ctx);
    // 4. output projection + LN1
    gemm_bt64<<<dim3(16, 32), 256, 0, stream>>>(ctx, Wot, ctxWo, 4096, 1024, 1024);
    k_ln<<<4096, 256, 0, stream>>>(ctxWo, bo, x, g1, be1, out1, out1b);
    // 5. FFN
    gemm_bt<1><<<dim3(32, 32), 256, 0, stream>>>(out1b, W1t, rb, 4096, 4096, 1024, b1);
    gemm_bt64<<<dim3(16, 32), 256, 0, stream>>>(rb, W2t, ff2, 4096, 1024, 4096);
    // 6. LN2 -> final output
    k_ln<<<4096, 256, 0, stream>>>(ff2, b2, out1, g2, be2, out, nullptr);
}